// Round 6
// baseline (1540.877 us; speedup 1.0000x reference)
//
#include <hip/hip_runtime.h>

#define NN 50000
#define EE 800000
#define BB 4096
#define NB 512       // dst buckets
#define BW 98        // nodes per bucket (512*98 >= 50000)
#define CH 128       // edge chunks per set in bucketA (800000/128 = 6250)

// f32 weight-table offsets (elements)
#define OFF_T1W 0
#define OFF_T1B 16384
#define OFF_GW1 16448
#define OFF_GB1 16832
#define OFF_HW1 16848
#define OFF_GW2 29136
#define OFF_GB2 30288
#define OFF_HW2 30304
#define OFF_T2W 67168
#define OFF_T2B 112224
#define OFF_T3W 112288
#define OFF_T3B 112416
#define WTOT    112418

// bf16 weight table (MFMA B-operands)
#define WB_T1W  0        // t1w native [64][256]
#define WB_HW1T 16384    // 3 x hw1^T [64][64]
#define WB_HW2T 28672    // 3 x hw2^T [64][192]
#define WB_T2W  65536    // t2w native [64][704]
#define WB_TOT  110592

typedef __attribute__((ext_vector_type(8))) short bf16x8;
typedef __attribute__((ext_vector_type(4))) float f32x4;

__device__ __forceinline__ float bf2f(unsigned short u) {
    return __uint_as_float(((unsigned int)u) << 16);
}
__device__ __forceinline__ unsigned short f2bf(float f) {
    unsigned int u = __float_as_uint(f);
    u = (u + 0x7fffu + ((u >> 16) & 1u)) >> 16;
    return (unsigned short)u;
}
__device__ __forceinline__ float leakyf(float v) { return v >= 0.f ? v : 0.3f * v; }
__device__ __forceinline__ float tanh_fast(float v) {
    float e = __expf(2.f * v);
    return 1.f - 2.f / (e + 1.f);
}

// ---------- dtype sniffer: 0 = bf16, 1 = f32 ----------
__global__ void k_sniff(const unsigned short* __restrict__ hs, int* __restrict__ flag) {
    int lane = threadIdx.x;
    unsigned short s = hs[2 * lane];
    int ef = (s >> 7) & 0xFF;
    unsigned long long m = __ballot(ef >= 100 && ef <= 132);
    if (lane == 0) flag[0] = (__popcll(m) >= 40) ? 0 : 1;
}

// ---------- convert all weight tensors to one f32 table ----------
__global__ __launch_bounds__(1024) void k_convert(
    const int* __restrict__ fl,
    const void* t1w, const void* t1b,
    const void* gw1a, const void* gw1b, const void* gw1c,
    const void* gb1a, const void* gb1b, const void* gb1c,
    const void* hw1a, const void* hw1b, const void* hw1c,
    const void* gw2a, const void* gw2b, const void* gw2c,
    const void* gb2a, const void* gb2b, const void* gb2c,
    const void* hw2a, const void* hw2b, const void* hw2c,
    const void* t2w, const void* t2b, const void* t3w, const void* t3b,
    float* __restrict__ fw) {
    const int starts[24] = {0, 16384, 16448, 16576, 16704, 16832, 16833, 16834,
                            16848, 20944, 25040, 29136, 29520, 29904, 30288, 30289, 30290,
                            30304, 42592, 54880, 67168, 112224, 112288, 112416};
    const int cnts[24] = {16384, 64, 128, 128, 128, 1, 1, 1, 4096, 4096, 4096,
                          384, 384, 384, 1, 1, 1, 12288, 12288, 12288, 45056, 64, 128, 2};
    const void* sp[24] = {t1w, t1b, gw1a, gw1b, gw1c, gb1a, gb1b, gb1c, hw1a, hw1b, hw1c,
                          gw2a, gw2b, gw2c, gb2a, gb2b, gb2c, hw2a, hw2b, hw2c, t2w, t2b, t3w, t3b};
    int isf32 = fl[0];
    int idx = blockIdx.x * 1024 + threadIdx.x;
    if (idx >= WTOT) return;
    float v = 0.f;
#pragma unroll
    for (int k = 0; k < 24; ++k) {
        int lo = idx - starts[k];
        if (lo >= 0 && lo < cnts[k])
            v = isf32 ? ((const float*)sp[k])[lo] : bf2f(((const unsigned short*)sp[k])[lo]);
    }
    fw[idx] = v;
}

// ---------- bf16 weight table: t1w, hw1^T, hw2^T, t2w ----------
__global__ __launch_bounds__(256) void k_convert16(const int* __restrict__ fl, const void* t1w,
                                                   const void* hw1a, const void* hw1b, const void* hw1c,
                                                   const void* hw2a, const void* hw2b, const void* hw2c,
                                                   const void* t2w, unsigned short* __restrict__ wb) {
    int idx = blockIdx.x * 256 + threadIdx.x;
    if (idx >= WB_TOT) return;
    int isf32 = fl[0];
    const void* p;
    int srci;
    if (idx < WB_HW1T) {
        p = t1w; srci = idx;
    } else if (idx < WB_HW2T) {
        int rel = idx - WB_HW1T;
        int set = rel >> 12, r2 = rel & 4095;
        int jj = r2 >> 6, kk = r2 & 63;          // hw1T[j][k] = hw1[k][j], [64][64]
        p = set == 0 ? hw1a : (set == 1 ? hw1b : hw1c);
        srci = kk * 64 + jj;
    } else if (idx < WB_T2W) {
        int rel = idx - WB_HW2T;
        int set = rel / 12288, r2 = rel % 12288;
        int n = r2 / 192, k = r2 % 192;          // hw2T[n][k] = hw2[k][n], hw2 [192][64]
        p = set == 0 ? hw2a : (set == 1 ? hw2b : hw2c);
        srci = k * 64 + n;
    } else {
        p = t2w; srci = idx - WB_T2W;            // t2w native [64][704]
    }
    wb[idx] = isf32 ? f2bf(((const float*)p)[srci]) : ((const unsigned short*)p)[srci];
}

// ---------- degree count ----------
__global__ __launch_bounds__(256) void k_deg(const int* __restrict__ d0, const int* __restrict__ d1,
                                             const int* __restrict__ d2, int* __restrict__ deg) {
    int set = blockIdx.y;
    const int* dd = set == 0 ? d0 : (set == 1 ? d1 : d2);
    int t = blockIdx.x * 256 + threadIdx.x;
    if (t < EE) atomicAdd(&deg[(size_t)set * NN + dd[t]], 1);
}

// ---------- d into .z of per-node float4 packs (x=ps, y=pd, z=d) ----------
__global__ __launch_bounds__(256) void k_dnorm(const int* __restrict__ deg, float* __restrict__ g1,
                                               float* __restrict__ g2) {
    int t = blockIdx.x * 256 + threadIdx.x;
    if (t < 3 * NN) {
        int g = deg[t];
        float v = g > 0 ? rsqrtf((float)g) : 0.f;
        g1[(size_t)t * 4 + 2] = v;
        g2[(size_t)t * 4 + 2] = v;
    }
}

// ---------- bucket sums from per-node degrees ----------
__global__ void k_bsum(const int* __restrict__ deg, int* __restrict__ bcnt) {
    int b = blockIdx.x, set = blockIdx.y;
    int lane = threadIdx.x;  // 64
    int nb = b * BW;
    int s = 0;
    for (int i = lane; i < BW; i += 64) {
        int n = nb + i;
        if (n < NN) s += deg[(size_t)set * NN + n];
    }
#pragma unroll
    for (int m = 32; m >= 1; m >>= 1) s += __shfl_xor(s, m);
    if (lane == 0) bcnt[set * NB + b] = s;
}

// ---------- per-set exclusive scan of bucket counts; init global cursors ----------
__global__ __launch_bounds__(512) void k_bscan(const int* __restrict__ bcnt, int* __restrict__ bbase,
                                               int* __restrict__ gcur) {
    int set = blockIdx.x;
    __shared__ int sh[NB];
    int tid = threadIdx.x;   // 512
    int v = bcnt[set * NB + tid];
    sh[tid] = v;
    __syncthreads();
    for (int off = 1; off < NB; off <<= 1) {
        int t = (tid >= off) ? sh[tid - off] : 0;
        __syncthreads();
        sh[tid] += t;
        __syncthreads();
    }
    int excl = sh[tid] - v;
    bbase[set * (NB + 1) + tid] = excl;
    gcur[set * NB + tid] = excl;
    if (tid == NB - 1) bbase[set * (NB + 1) + NB] = sh[tid];
}

// ---------- mark batch nodes, assign compact slots ----------
__global__ __launch_bounds__(256) void k_mark(const int* __restrict__ nodes, int* __restrict__ mark,
                                              int* __restrict__ slotof, int* __restrict__ cnt) {
    int b = blockIdx.x * 256 + threadIdx.x;
    if (b < BB) {
        int n = nodes[b];
        if (atomicCAS(&mark[n], 0, 1) == 0) {
            int s = atomicAdd(cnt, 1);
            slotof[n] = s;
        }
    }
}

// ---------- input transform via MFMA: x = leaky(h @ t1w^T + b), fused p1 gate dots ----------
__global__ __launch_bounds__(256) void k_input(const int* __restrict__ fl,
                                               const void* __restrict__ hB,
                                               const unsigned short* __restrict__ wb,
                                               const float* __restrict__ fw,
                                               unsigned short* __restrict__ x16,
                                               float4* __restrict__ g1v4) {
    __shared__ float xt[16][65];
    int tid = threadIdx.x, lane = tid & 63, wid = tid >> 6;
    int m = lane & 15, q = lane >> 4;
    int node0 = blockIdx.x * 16;
    int isf32 = fl[0];
    f32x4 acc = {0.f, 0.f, 0.f, 0.f};
    const unsigned short* bsrc = wb + WB_T1W + ((size_t)(wid * 16 + m)) * 256 + q * 8;
    if (isf32) {
        const float* ap = (const float*)hB + (size_t)(node0 + m) * 256 + q * 8;
        for (int k0 = 0; k0 < 256; k0 += 32) {
            float4 f0 = *(const float4*)(ap + k0);
            float4 f1 = *(const float4*)(ap + k0 + 4);
            bf16x8 a;
            a[0] = (short)f2bf(f0.x); a[1] = (short)f2bf(f0.y);
            a[2] = (short)f2bf(f0.z); a[3] = (short)f2bf(f0.w);
            a[4] = (short)f2bf(f1.x); a[5] = (short)f2bf(f1.y);
            a[6] = (short)f2bf(f1.z); a[7] = (short)f2bf(f1.w);
            bf16x8 b = *(const bf16x8*)(bsrc + k0);
            acc = __builtin_amdgcn_mfma_f32_16x16x32_bf16(a, b, acc, 0, 0, 0);
        }
    } else {
        const unsigned short* ap = (const unsigned short*)hB + (size_t)(node0 + m) * 256 + q * 8;
        for (int k0 = 0; k0 < 256; k0 += 32) {
            bf16x8 a = *(const bf16x8*)(ap + k0);
            bf16x8 b = *(const bf16x8*)(bsrc + k0);
            acc = __builtin_amdgcn_mfma_f32_16x16x32_bf16(a, b, acc, 0, 0, 0);
        }
    }
    int gcol = wid * 16 + m;
    float bias = fw[OFF_T1B + gcol];
#pragma unroll
    for (int r = 0; r < 4; ++r) {
        int row = q * 4 + r;
        float v = leakyf(acc[r] + bias);
        x16[(size_t)(node0 + row) * 64 + gcol] = f2bf(v);
        xt[row][gcol] = v;
    }
    __syncthreads();
    int nl = wid * 4 + q;
    int node = node0 + nl;
    float xv[4];
#pragma unroll
    for (int r = 0; r < 4; ++r) xv[r] = xt[nl][m + 16 * r];
#pragma unroll
    for (int set = 0; set < 3; ++set) {
        const float* gw = fw + OFF_GW1 + set * 128;
        float pd = 0.f, ps = 0.f;
#pragma unroll
        for (int r = 0; r < 4; ++r) {
            int c = m + 16 * r;
            pd = fmaf(xv[r], gw[c], pd);
            ps = fmaf(xv[r], gw[64 + c], ps);
        }
        pd += __shfl_xor(pd, 1); ps += __shfl_xor(ps, 1);
        pd += __shfl_xor(pd, 2); ps += __shfl_xor(ps, 2);
        pd += __shfl_xor(pd, 4); ps += __shfl_xor(ps, 4);
        pd += __shfl_xor(pd, 8); ps += __shfl_xor(ps, 8);
        if (m == 0) {
            float2* p = (float2*)&g1v4[(size_t)set * NN + node];
            *p = make_float2(ps, pd);   // .x=ps, .y=pd
        }
    }
}

// ---------- multi-split bucket scatter: two-pass LDS histogram, burst-contiguous writes ----------
__global__ __launch_bounds__(256) void k_bucketA(const int* __restrict__ s0, const int* __restrict__ s1,
                                                 const int* __restrict__ s2, const int* __restrict__ d0,
                                                 const int* __restrict__ d1, const int* __restrict__ d2,
                                                 int* __restrict__ gcur, unsigned int* __restrict__ tmp) {
    int set = blockIdx.y;
    const int* ss = set == 0 ? s0 : (set == 1 ? s1 : s2);
    const int* dd = set == 0 ? d0 : (set == 1 ? d1 : d2);
    __shared__ int hist[NB];
    __shared__ int lcur[NB];
    int tid = threadIdx.x;
    for (int i = tid; i < NB; i += 256) { hist[i] = 0; lcur[i] = 0; }
    __syncthreads();
    int e0 = blockIdx.x * (EE / CH);
    int e1 = e0 + (EE / CH);
    for (int t = e0 + tid; t < e1; t += 256)
        atomicAdd(&hist[dd[t] / BW], 1);
    __syncthreads();
    for (int b = tid; b < NB; b += 256) {
        int hh = hist[b];
        if (hh > 0) hist[b] = atomicAdd(&gcur[set * NB + b], hh);
    }
    __syncthreads();
    unsigned int* tp = tmp + (size_t)set * EE;
    for (int t = e0 + tid; t < e1; t += 256) {
        int d = dd[t], s = ss[t];
        int b = d / BW;
        int r = atomicAdd(&lcur[b], 1);
        tp[hist[b] + r] = (unsigned)s | ((unsigned)(d - b * BW) << 16);
    }
}

// ---------- layer 1 bucket aggregation: inline gate, LDS f32 acc, MFMA hw1 epilogue ----------
#define ACCR 112
__global__ __launch_bounds__(256) void k_agg1(const unsigned short* __restrict__ x16,
                                              const unsigned int* __restrict__ tmp,
                                              const int* __restrict__ bbase,
                                              const float4* __restrict__ g1v4,
                                              const float* __restrict__ fw,
                                              const unsigned short* __restrict__ wb,
                                              unsigned short* __restrict__ raw2_16) {
    int b = blockIdx.x, set = blockIdx.y;
    int nb = b * BW;
    if (nb >= NN) return;
    __shared__ float acc[ACCR * 64];         // 28 KB
    __shared__ float4 gdw[BW];               // 1.5 KB
    __shared__ int2 elist[2048];             // 16 KB
    __shared__ unsigned short tb[16][72];    // 2.3 KB
    int tid = threadIdx.x, lane = tid & 63, wid = tid >> 6;
    int nv = NN - nb < BW ? NN - nb : BW;
    for (int i = tid; i < ACCR * 64; i += 256) acc[i] = 0.f;
    if (tid < nv) gdw[tid] = g1v4[(size_t)set * NN + nb + tid];
    int base = bbase[set * (NB + 1) + b];
    int cnt = bbase[set * (NB + 1) + b + 1] - base;
    float gbv = fw[OFF_GB1 + set];
    __syncthreads();
    const float4* gv = g1v4 + (size_t)set * NN;
    const unsigned int* tp = tmp + (size_t)set * EE + base;
    for (int c0 = 0; c0 < cnt; c0 += 2048) {
        int cc = cnt - c0 < 2048 ? cnt - c0 : 2048;
        for (int j = tid; j < cc; j += 256) {
            unsigned rec = tp[c0 + j];
            int s = rec & 0xFFFF;
            int dl = rec >> 16;
            float4 gs = gv[s];
            float4 gd = gdw[dl];
            float a = tanh_fast(gd.y + gs.x + gbv);
            elist[j] = make_int2((int)rec, __float_as_int(a * gd.z * gs.z));
        }
        __syncthreads();
        int per = (cc + 3) >> 2;
        int j0 = wid * per;
        int j1 = j0 + per < cc ? j0 + per : cc;
        int j = j0;
        for (; j + 4 <= j1; j += 4) {
            int2 r0 = elist[j], r1 = elist[j + 1], r2 = elist[j + 2], r3 = elist[j + 3];
            float v0 = bf2f(x16[(size_t)(r0.x & 0xFFFF) * 64 + lane]);
            float v1 = bf2f(x16[(size_t)(r1.x & 0xFFFF) * 64 + lane]);
            float v2 = bf2f(x16[(size_t)(r2.x & 0xFFFF) * 64 + lane]);
            float v3 = bf2f(x16[(size_t)(r3.x & 0xFFFF) * 64 + lane]);
            atomicAdd(&acc[(r0.x >> 16) * 64 + lane], v0 * __int_as_float(r0.y));
            atomicAdd(&acc[(r1.x >> 16) * 64 + lane], v1 * __int_as_float(r1.y));
            atomicAdd(&acc[(r2.x >> 16) * 64 + lane], v2 * __int_as_float(r2.y));
            atomicAdd(&acc[(r3.x >> 16) * 64 + lane], v3 * __int_as_float(r3.y));
        }
        for (; j < j1; ++j) {
            int2 r0 = elist[j];
            float v0 = bf2f(x16[(size_t)(r0.x & 0xFFFF) * 64 + lane]);
            atomicAdd(&acc[(r0.x >> 16) * 64 + lane], v0 * __int_as_float(r0.y));
        }
        __syncthreads();
    }
    // epilogue: eps residual + hw1 GEMV via MFMA, 16-row tiles
    int m = lane & 15, q = lane >> 4;
    for (int t0 = 0; t0 < BW; t0 += 16) {
#pragma unroll
        for (int it = 0; it < 4; ++it) {
            int idx = tid + it * 256;
            int r = idx >> 6, c = idx & 63;
            int row = t0 + r;
            float t = 0.f;
            if (row < nv)
                t = fmaf(0.3f, bf2f(x16[(size_t)(nb + row) * 64 + c]), acc[row * 64 + c]);
            tb[r][c] = f2bf(t);
        }
        __syncthreads();
        f32x4 c4 = {0.f, 0.f, 0.f, 0.f};
        const unsigned short* bp = wb + WB_HW1T + set * 4096 + (wid * 16 + m) * 64 + q * 8;
#pragma unroll
        for (int k0 = 0; k0 < 64; k0 += 32) {
            bf16x8 a = *(const bf16x8*)&tb[m][k0 + q * 8];
            bf16x8 bb = *(const bf16x8*)(bp + k0);
            c4 = __builtin_amdgcn_mfma_f32_16x16x32_bf16(a, bb, c4, 0, 0, 0);
        }
        int gcol = wid * 16 + m;
#pragma unroll
        for (int r = 0; r < 4; ++r) {
            int row = t0 + q * 4 + r;
            if (row < nv)
                raw2_16[(size_t)(nb + row) * 192 + set * 64 + gcol] = f2bf(leakyf(c4[r]));
        }
        __syncthreads();
    }
}

// ---------- layer-2 gate scalars from raw2 ----------
__global__ __launch_bounds__(1024) void k_p2(const unsigned short* __restrict__ raw2_16,
                                             const float* __restrict__ fw,
                                             float4* __restrict__ g2v4) {
    int tid = threadIdx.x, lane = tid & 63, wid = tid >> 6;
    int node = blockIdx.x * 16 + wid;
    const unsigned short* r = raw2_16 + (size_t)node * 192;
    float v0 = bf2f(r[lane]);
    float v1 = bf2f(r[64 + lane]);
    float v2 = bf2f(r[128 + lane]);
#pragma unroll
    for (int k = 0; k < 3; ++k) {
        const float* g = fw + OFF_GW2 + k * 384;
        float pd = v0 * g[lane] + v1 * g[64 + lane] + v2 * g[128 + lane];
        float ps = v0 * g[192 + lane] + v1 * g[256 + lane] + v2 * g[320 + lane];
#pragma unroll
        for (int mm = 32; mm >= 1; mm >>= 1) { pd += __shfl_xor(pd, mm); ps += __shfl_xor(ps, mm); }
        if (lane == 0) {
            float2* p = (float2*)&g2v4[(size_t)k * NN + node];
            *p = make_float2(ps, pd);
        }
    }
}

// ---------- layer 2 bucket aggregation, marked dst only ----------
__global__ __launch_bounds__(256) void k_agg2(const unsigned short* __restrict__ raw2_16,
                                              const unsigned int* __restrict__ tmp,
                                              const int* __restrict__ bbase,
                                              const float4* __restrict__ g2v4,
                                              const float* __restrict__ fw,
                                              const int* __restrict__ mark,
                                              const int* __restrict__ slotof,
                                              float* __restrict__ z2) {
    int b = blockIdx.x, set = blockIdx.y;
    int nb = b * BW;
    if (nb >= NN) return;
    __shared__ float acc[16 * 192];      // 12 KB
    __shared__ float4 gdw[BW];
    __shared__ int mloc[BW];
    __shared__ int zslot[16];
    __shared__ int mlist_s[1024];
    __shared__ float mlist_e[1024];
    __shared__ int mcnt, nmk;
    int tid = threadIdx.x, lane = tid & 63, wid = tid >> 6;
    int nv = NN - nb < BW ? NN - nb : BW;
    if (tid < BW) mloc[tid] = -1;
    if (tid < nv) gdw[tid] = g2v4[(size_t)set * NN + nb + tid];
    __syncthreads();
    if (tid == 0) {
        int c = 0;
        for (int i = 0; i < nv; ++i)
            if (mark[nb + i]) mloc[i] = c++;
        nmk = c;
    }
    __syncthreads();
    int nm = nmk;
    if (nm == 0) return;
    int base = bbase[set * (NB + 1) + b];
    int cnt = bbase[set * (NB + 1) + b + 1] - base;
    float gbv = fw[OFF_GB2 + set];
    const float4* gv = g2v4 + (size_t)set * NN;
    const unsigned int* tp = tmp + (size_t)set * EE + base;
    for (int c0 = 0; c0 < nm; c0 += 16) {
        for (int i = tid; i < 16 * 192; i += 256) acc[i] = 0.f;
        if (tid == 0) mcnt = 0;
        __syncthreads();
        for (int j = tid; j < cnt; j += 256) {
            unsigned rec = tp[j];
            int dl = rec >> 16;
            int ml = mloc[dl];
            if (ml < c0 || ml >= c0 + 16) continue;
            int s = rec & 0xFFFF;
            float4 gs = gv[s];
            float4 gd = gdw[dl];
            float a = tanh_fast(gd.y + gs.x + gbv);
            int p = atomicAdd(&mcnt, 1);
            if (p < 1024) { mlist_s[p] = s | ((ml - c0) << 16); mlist_e[p] = a * gd.z * gs.z; }
        }
        __syncthreads();
        int mm2 = mcnt < 1024 ? mcnt : 1024;
        int per = (mm2 + 3) >> 2;
        int j0 = wid * per;
        int j1 = j0 + per < mm2 ? j0 + per : mm2;
        for (int j = j0; j < j1; ++j) {
            int sp = mlist_s[j];
            int s = sp & 0xFFFF;
            int cs = sp >> 16;
            float e = mlist_e[j];
            const unsigned short* r = raw2_16 + (size_t)s * 192;
            atomicAdd(&acc[cs * 192 + lane], bf2f(r[lane]) * e);
            atomicAdd(&acc[cs * 192 + 64 + lane], bf2f(r[64 + lane]) * e);
            atomicAdd(&acc[cs * 192 + 128 + lane], bf2f(r[128 + lane]) * e);
        }
        __syncthreads();
        if (tid < 16) {
            int found = -1;
            for (int i = 0; i < nv; ++i)
                if (mloc[i] == c0 + tid) { found = nb + i; break; }
            zslot[tid] = (found >= 0) ? slotof[found] : -1;
        }
        __syncthreads();
        for (int i = tid; i < 16 * 192; i += 256) {
            int cs = i / 192, c = i % 192;
            int zs = zslot[cs];
            if (zs >= 0) z2[(size_t)zs * 576 + set * 192 + c] = acc[i];
        }
        __syncthreads();
    }
}

// ---------- final: 16 rows/block, MFMA hw2 + t2 GEMMs, t3 epilogue ----------
__global__ __launch_bounds__(256) void k_final(const int* __restrict__ fl,
                                               const int* __restrict__ nodes,
                                               const int* __restrict__ slotof,
                                               const float* __restrict__ z2,
                                               const unsigned short* __restrict__ raw2_16,
                                               const unsigned short* __restrict__ x16,
                                               const void* __restrict__ hB,
                                               const float* __restrict__ fw,
                                               const unsigned short* __restrict__ wb,
                                               void* __restrict__ outv) {
    __shared__ unsigned short nfb[16][712];
    __shared__ unsigned short tbb[16][200];
    __shared__ float sarr[16][64];
    __shared__ int nd[16], sl[16];
    int tid = threadIdx.x, lane = tid & 63, wid = tid >> 6;
    int m = lane & 15, q = lane >> 4;
    int b0 = blockIdx.x * 16;
    int isf32 = fl[0];
    if (tid < 16) {
        int n = nodes[b0 + tid];
        nd[tid] = n;
        sl[tid] = slotof[n];
    }
    __syncthreads();
    for (int idx = tid; idx < 16 * 256; idx += 256) {
        int row = idx >> 8, c = idx & 255;
        size_t hi = (size_t)nd[row] * 256 + c;
        nfb[row][192 + c] = isf32 ? f2bf(((const float*)hB)[hi]) : ((const unsigned short*)hB)[hi];
    }
    for (int idx = tid; idx < 16 * 64; idx += 256) {
        int row = idx >> 6, c = idx & 63;
        nfb[row][448 + c] = x16[(size_t)nd[row] * 64 + c];
    }
    for (int idx = tid; idx < 16 * 192; idx += 256) {
        int row = idx / 192, c = idx % 192;
        nfb[row][512 + c] = raw2_16[(size_t)nd[row] * 192 + c];
    }
    for (int set = 0; set < 3; ++set) {
        __syncthreads();
        for (int idx = tid; idx < 16 * 192; idx += 256) {
            int row = idx / 192, c = idx % 192;
            float r2 = bf2f(nfb[row][512 + c]);
            tbb[row][c] = f2bf(fmaf(0.3f, r2, z2[(size_t)sl[row] * 576 + set * 192 + c]));
        }
        __syncthreads();
        f32x4 c4 = {0.f, 0.f, 0.f, 0.f};
        const unsigned short* bp = wb + WB_HW2T + set * 12288 + (wid * 16 + m) * 192 + q * 8;
#pragma unroll
        for (int k0 = 0; k0 < 192; k0 += 32) {
            bf16x8 a = *(const bf16x8*)&tbb[m][k0 + q * 8];
            bf16x8 bf = *(const bf16x8*)(bp + k0);
            c4 = __builtin_amdgcn_mfma_f32_16x16x32_bf16(a, bf, c4, 0, 0, 0);
        }
        int col = wid * 16 + m;
#pragma unroll
        for (int r = 0; r < 4; ++r)
            nfb[q * 4 + r][set * 64 + col] = f2bf(leakyf(c4[r]));
    }
    __syncthreads();
    f32x4 c4 = {0.f, 0.f, 0.f, 0.f};
    const unsigned short* bp = wb + WB_T2W + (wid * 16 + m) * 704 + q * 8;
#pragma unroll
    for (int k0 = 0; k0 < 704; k0 += 32) {
        bf16x8 a = *(const bf16x8*)&nfb[m][k0 + q * 8];
        bf16x8 bf = *(const bf16x8*)(bp + k0);
        c4 = __builtin_amdgcn_mfma_f32_16x16x32_bf16(a, bf, c4, 0, 0, 0);
    }
    int col = wid * 16 + m;
    float bias = fw[OFF_T2B + col];
#pragma unroll
    for (int r = 0; r < 4; ++r) {
        int row = q * 4 + r;
        float sv = leakyf(c4[r] + bias);
        sarr[row][col] = sv;
        size_t oi = 8192 + (size_t)(b0 + row) * 64 + col;
        if (isf32) ((float*)outv)[oi] = sv;
        else ((unsigned short*)outv)[oi] = f2bf(sv);
    }
    __syncthreads();
    if (tid < 32) {
        int row = tid >> 1, oc = tid & 1;
        float acc2 = fw[OFF_T3B + oc];
        const float* tw = fw + OFF_T3W + oc * 64;
#pragma unroll 8
        for (int c = 0; c < 64; ++c) acc2 = fmaf(sarr[row][c], tw[c], acc2);
        size_t oi = (size_t)(b0 + row) * 2 + oc;
        if (isf32) ((float*)outv)[oi] = acc2;
        else ((unsigned short*)outv)[oi] = f2bf(acc2);
    }
}

extern "C" void kernel_launch(void* const* d_in, const int* in_sizes, int n_in,
                              void* d_out, int out_size, void* d_ws, size_t ws_size,
                              hipStream_t stream) {
    const void* h = d_in[0];
    const int* src1 = (const int*)d_in[1];
    const int* dst1 = (const int*)d_in[2];
    const int* src2 = (const int*)d_in[3];
    const int* dst2 = (const int*)d_in[4];
    const int* src3 = (const int*)d_in[5];
    const int* dst3 = (const int*)d_in[6];
    const int* nodes = (const int*)d_in[7];

    char* w = (char*)d_ws;
    size_t off = 0;
    auto carve = [&](size_t bytes) -> void* {
        void* p = w + off;
        off += (bytes + 255) & ~(size_t)255;
        return p;
    };
    int* flag = (int*)carve(256);
    int* deg = (int*)carve((size_t)3 * NN * 4);        // zeroed
    int* mark = (int*)carve((size_t)NN * 4);           // zeroed
    int* cntp = (int*)carve(256);                      // zeroed
    int* bcnt = (int*)carve((size_t)3 * NB * 4);
    int* bbase = (int*)carve((size_t)3 * (NB + 1) * 4);
    int* gcur = (int*)carve((size_t)3 * NB * 4);
    float4* g1v4 = (float4*)carve((size_t)3 * NN * 16);
    float4* g2v4 = (float4*)carve((size_t)3 * NN * 16);
    unsigned int* tmp = (unsigned int*)carve((size_t)3 * EE * 4);
    float* fw = (float*)carve((size_t)WTOT * 4);
    unsigned short* wb = (unsigned short*)carve((size_t)WB_TOT * 2);
    unsigned short* x16 = (unsigned short*)carve((size_t)NN * 64 * 2);
    unsigned short* raw2_16 = (unsigned short*)carve((size_t)NN * 192 * 2);
    int* slotof = (int*)carve((size_t)NN * 4);
    float* z2 = (float*)carve((size_t)BB * 576 * 4);

    size_t zbytes = (size_t)((char*)cntp - (char*)deg) + 256;
    hipMemsetAsync(deg, 0, zbytes, stream);

    k_sniff<<<1, 64, 0, stream>>>((const unsigned short*)h, flag);
    k_convert<<<(WTOT + 1023) / 1024, 1024, 0, stream>>>(
        flag, d_in[8], d_in[9],
        d_in[10], d_in[16], d_in[22],
        d_in[11], d_in[17], d_in[23],
        d_in[12], d_in[18], d_in[24],
        d_in[13], d_in[19], d_in[25],
        d_in[14], d_in[20], d_in[26],
        d_in[15], d_in[21], d_in[27],
        d_in[28], d_in[29], d_in[30], d_in[31], fw);
    k_convert16<<<(WB_TOT + 255) / 256, 256, 0, stream>>>(flag, d_in[8],
                                                          d_in[12], d_in[18], d_in[24],
                                                          d_in[15], d_in[21], d_in[27],
                                                          d_in[28], wb);

    dim3 ge(3125, 3);
    k_deg<<<ge, 256, 0, stream>>>(dst1, dst2, dst3, deg);
    k_dnorm<<<(3 * NN + 255) / 256, 256, 0, stream>>>(deg, (float*)g1v4, (float*)g2v4);
    dim3 gb(NB, 3);
    k_bsum<<<gb, 64, 0, stream>>>(deg, bcnt);
    k_bscan<<<3, NB, 0, stream>>>(bcnt, bbase, gcur);
    k_mark<<<(BB + 255) / 256, 256, 0, stream>>>(nodes, mark, slotof, cntp);

    dim3 gch(CH, 3);
    k_bucketA<<<gch, 256, 0, stream>>>(src1, src2, src3, dst1, dst2, dst3, gcur, tmp);
    k_input<<<3125, 256, 0, stream>>>(flag, h, wb, fw, x16, g1v4);

    k_agg1<<<gb, 256, 0, stream>>>(x16, tmp, bbase, g1v4, fw, wb, raw2_16);
    k_p2<<<3125, 1024, 0, stream>>>(raw2_16, fw, g2v4);
    k_agg2<<<gb, 256, 0, stream>>>(raw2_16, tmp, bbase, g2v4, fw, mark, slotof, z2);
    k_final<<<BB / 16, 256, 0, stream>>>(flag, nodes, slotof, z2, raw2_16, x16, h, fw, wb, d_out);
}

// Round 7
// 432.211 us; speedup vs baseline: 3.5651x; 3.5651x over previous
//
#include <hip/hip_runtime.h>

#define NN 50000
#define EE 800000
#define BB 4096
#define NB 512       // dst buckets
#define BW 98        // nodes per bucket
#define CAP 2176     // slot capacity per bucket (mean 1568 + ~15 sigma)
#define CH 128       // edge chunks per set in bucketA

// f32 weight-table offsets (elements)
#define OFF_T1W 0
#define OFF_T1B 16384
#define OFF_GW1 16448
#define OFF_GB1 16832
#define OFF_HW1 16848
#define OFF_GW2 29136
#define OFF_GB2 30288
#define OFF_HW2 30304
#define OFF_T2W 67168
#define OFF_T2B 112224
#define OFF_T3W 112288
#define OFF_T3B 112416
#define WTOT    112418

// bf16 weight table (MFMA B-operands)
#define WB_T1W  0        // t1w native [64][256]
#define WB_HW1T 16384    // 3 x hw1^T [64][64]
#define WB_HW2T 28672    // 3 x hw2^T [64][192]
#define WB_T2W  65536    // t2w native [64][704]
#define WB_TOT  110592

typedef __attribute__((ext_vector_type(8))) short bf16x8;
typedef __attribute__((ext_vector_type(4))) float f32x4;

__device__ __forceinline__ float bf2f(unsigned short u) {
    return __uint_as_float(((unsigned int)u) << 16);
}
__device__ __forceinline__ unsigned short f2bf(float f) {
    unsigned int u = __float_as_uint(f);
    u = (u + 0x7fffu + ((u >> 16) & 1u)) >> 16;
    return (unsigned short)u;
}
__device__ __forceinline__ float leakyf(float v) { return v >= 0.f ? v : 0.3f * v; }
__device__ __forceinline__ float tanh_fast(float v) {
    float e = __expf(2.f * v);
    return 1.f - 2.f / (e + 1.f);
}
__device__ __forceinline__ int rfl(int v) { return __builtin_amdgcn_readfirstlane(v); }

// ---------- dtype sniffer: 0 = bf16, 1 = f32 ----------
__global__ void k_sniff(const unsigned short* __restrict__ hs, int* __restrict__ flag) {
    int lane = threadIdx.x;
    unsigned short s = hs[2 * lane];
    int ef = (s >> 7) & 0xFF;
    unsigned long long m = __ballot(ef >= 100 && ef <= 132);
    if (lane == 0) flag[0] = (__popcll(m) >= 40) ? 0 : 1;
}

// ---------- convert all weight tensors to one f32 table ----------
__global__ __launch_bounds__(1024) void k_convert(
    const int* __restrict__ fl,
    const void* t1w, const void* t1b,
    const void* gw1a, const void* gw1b, const void* gw1c,
    const void* gb1a, const void* gb1b, const void* gb1c,
    const void* hw1a, const void* hw1b, const void* hw1c,
    const void* gw2a, const void* gw2b, const void* gw2c,
    const void* gb2a, const void* gb2b, const void* gb2c,
    const void* hw2a, const void* hw2b, const void* hw2c,
    const void* t2w, const void* t2b, const void* t3w, const void* t3b,
    float* __restrict__ fw) {
    const int starts[24] = {0, 16384, 16448, 16576, 16704, 16832, 16833, 16834,
                            16848, 20944, 25040, 29136, 29520, 29904, 30288, 30289, 30290,
                            30304, 42592, 54880, 67168, 112224, 112288, 112416};
    const int cnts[24] = {16384, 64, 128, 128, 128, 1, 1, 1, 4096, 4096, 4096,
                          384, 384, 384, 1, 1, 1, 12288, 12288, 12288, 45056, 64, 128, 2};
    const void* sp[24] = {t1w, t1b, gw1a, gw1b, gw1c, gb1a, gb1b, gb1c, hw1a, hw1b, hw1c,
                          gw2a, gw2b, gw2c, gb2a, gb2b, gb2c, hw2a, hw2b, hw2c, t2w, t2b, t3w, t3b};
    int isf32 = fl[0];
    int idx = blockIdx.x * 1024 + threadIdx.x;
    if (idx >= WTOT) return;
    float v = 0.f;
#pragma unroll
    for (int k = 0; k < 24; ++k) {
        int lo = idx - starts[k];
        if (lo >= 0 && lo < cnts[k])
            v = isf32 ? ((const float*)sp[k])[lo] : bf2f(((const unsigned short*)sp[k])[lo]);
    }
    fw[idx] = v;
}

// ---------- bf16 weight table: t1w, hw1^T, hw2^T, t2w ----------
__global__ __launch_bounds__(256) void k_convert16(const int* __restrict__ fl, const void* t1w,
                                                   const void* hw1a, const void* hw1b, const void* hw1c,
                                                   const void* hw2a, const void* hw2b, const void* hw2c,
                                                   const void* t2w, unsigned short* __restrict__ wb) {
    int idx = blockIdx.x * 256 + threadIdx.x;
    if (idx >= WB_TOT) return;
    int isf32 = fl[0];
    const void* p;
    int srci;
    if (idx < WB_HW1T) {
        p = t1w; srci = idx;
    } else if (idx < WB_HW2T) {
        int rel = idx - WB_HW1T;
        int set = rel >> 12, r2 = rel & 4095;
        int jj = r2 >> 6, kk = r2 & 63;
        p = set == 0 ? hw1a : (set == 1 ? hw1b : hw1c);
        srci = kk * 64 + jj;
    } else if (idx < WB_T2W) {
        int rel = idx - WB_HW2T;
        int set = rel / 12288, r2 = rel % 12288;
        int n = r2 / 192, k = r2 % 192;
        p = set == 0 ? hw2a : (set == 1 ? hw2b : hw2c);
        srci = k * 64 + n;
    } else {
        p = t2w; srci = idx - WB_T2W;
    }
    wb[idx] = isf32 ? f2bf(((const float*)p)[srci]) : ((const unsigned short*)p)[srci];
}

// ---------- multi-split bucket scatter: two-pass LDS histogram, slot-capped buckets ----------
__global__ __launch_bounds__(256) void k_bucketA(const int* __restrict__ s0, const int* __restrict__ s1,
                                                 const int* __restrict__ s2, const int* __restrict__ d0,
                                                 const int* __restrict__ d1, const int* __restrict__ d2,
                                                 int* __restrict__ gcur, unsigned int* __restrict__ tmp) {
    int set = blockIdx.y;
    const int* ss = set == 0 ? s0 : (set == 1 ? s1 : s2);
    const int* dd = set == 0 ? d0 : (set == 1 ? d1 : d2);
    __shared__ int hist[NB];
    __shared__ int lcur[NB];
    int tid = threadIdx.x;
    for (int i = tid; i < NB; i += 256) { hist[i] = 0; lcur[i] = 0; }
    __syncthreads();
    int e0 = blockIdx.x * (EE / CH);
    int e1 = e0 + (EE / CH);
    for (int t = e0 + tid; t < e1; t += 256)
        atomicAdd(&hist[dd[t] / BW], 1);
    __syncthreads();
    for (int b = tid; b < NB; b += 256) {
        int hh = hist[b];
        if (hh > 0) hist[b] = atomicAdd(&gcur[set * NB + b], hh);
    }
    __syncthreads();
    unsigned int* tp = tmp + (size_t)set * NB * CAP;
    for (int t = e0 + tid; t < e1; t += 256) {
        int d = dd[t], s = ss[t];
        int b = d / BW;
        int r = atomicAdd(&lcur[b], 1);
        int pos = hist[b] + r;
        if (pos < CAP) tp[(size_t)b * CAP + pos] = (unsigned)s | ((unsigned)(d - b * BW) << 16);
    }
}

// ---------- per-bucket: node degrees, rowptr (slot-relative), rsqrt d ----------
__global__ __launch_bounds__(256) void k_rowptr(const int* __restrict__ gcur,
                                                const unsigned int* __restrict__ tmp,
                                                int* __restrict__ deg, int* __restrict__ rowptr,
                                                float* __restrict__ g1, float* __restrict__ g2) {
    int b = blockIdx.x, set = blockIdx.y;
    int nb = b * BW;
    if (nb >= NN) return;
    __shared__ int hist[BW];
    __shared__ int rp[BW];
    int tid = threadIdx.x;
    int nv = NN - nb < BW ? NN - nb : BW;
    if (tid < BW) hist[tid] = 0;
    __syncthreads();
    int cnt = gcur[set * NB + b];
    if (cnt > CAP) cnt = CAP;
    const unsigned int* tp = tmp + (size_t)set * NB * CAP + (size_t)b * CAP;
    for (int j = tid; j < cnt; j += 256) atomicAdd(&hist[tp[j] >> 16], 1);
    __syncthreads();
    if (tid == 0) {
        int run = 0;
        for (int i = 0; i < nv; ++i) { rp[i] = run; run += hist[i]; }
    }
    __syncthreads();
    if (tid < nv) {
        int dg = hist[tid];
        size_t n = (size_t)set * NN + nb + tid;
        deg[n] = dg;
        rowptr[n] = b * CAP + rp[tid];
        float v = dg > 0 ? rsqrtf((float)dg) : 0.f;
        g1[n * 4 + 2] = v;
        g2[n * 4 + 2] = v;
    }
}

// ---------- input transform via MFMA: x = leaky(h @ t1w^T + b), fused p1 gate dots ----------
__global__ __launch_bounds__(256) void k_input(const int* __restrict__ fl,
                                               const void* __restrict__ hB,
                                               const unsigned short* __restrict__ wb,
                                               const float* __restrict__ fw,
                                               unsigned short* __restrict__ x16,
                                               float4* __restrict__ g1v4) {
    __shared__ float xt[16][65];
    int tid = threadIdx.x, lane = tid & 63, wid = tid >> 6;
    int m = lane & 15, q = lane >> 4;
    int node0 = blockIdx.x * 16;
    int isf32 = fl[0];
    f32x4 acc = {0.f, 0.f, 0.f, 0.f};
    const unsigned short* bsrc = wb + WB_T1W + ((size_t)(wid * 16 + m)) * 256 + q * 8;
    if (isf32) {
        const float* ap = (const float*)hB + (size_t)(node0 + m) * 256 + q * 8;
        for (int k0 = 0; k0 < 256; k0 += 32) {
            float4 f0 = *(const float4*)(ap + k0);
            float4 f1 = *(const float4*)(ap + k0 + 4);
            bf16x8 a;
            a[0] = (short)f2bf(f0.x); a[1] = (short)f2bf(f0.y);
            a[2] = (short)f2bf(f0.z); a[3] = (short)f2bf(f0.w);
            a[4] = (short)f2bf(f1.x); a[5] = (short)f2bf(f1.y);
            a[6] = (short)f2bf(f1.z); a[7] = (short)f2bf(f1.w);
            bf16x8 b = *(const bf16x8*)(bsrc + k0);
            acc = __builtin_amdgcn_mfma_f32_16x16x32_bf16(a, b, acc, 0, 0, 0);
        }
    } else {
        const unsigned short* ap = (const unsigned short*)hB + (size_t)(node0 + m) * 256 + q * 8;
        for (int k0 = 0; k0 < 256; k0 += 32) {
            bf16x8 a = *(const bf16x8*)(ap + k0);
            bf16x8 b = *(const bf16x8*)(bsrc + k0);
            acc = __builtin_amdgcn_mfma_f32_16x16x32_bf16(a, b, acc, 0, 0, 0);
        }
    }
    int gcol = wid * 16 + m;
    float bias = fw[OFF_T1B + gcol];
#pragma unroll
    for (int r = 0; r < 4; ++r) {
        int row = q * 4 + r;
        float v = leakyf(acc[r] + bias);
        x16[(size_t)(node0 + row) * 64 + gcol] = f2bf(v);
        xt[row][gcol] = v;
    }
    __syncthreads();
    int nl = wid * 4 + q;
    int node = node0 + nl;
    float xv[4];
#pragma unroll
    for (int r = 0; r < 4; ++r) xv[r] = xt[nl][m + 16 * r];
#pragma unroll
    for (int set = 0; set < 3; ++set) {
        const float* gw = fw + OFF_GW1 + set * 128;
        float pd = 0.f, ps = 0.f;
#pragma unroll
        for (int r = 0; r < 4; ++r) {
            int c = m + 16 * r;
            pd = fmaf(xv[r], gw[c], pd);
            ps = fmaf(xv[r], gw[64 + c], ps);
        }
        pd += __shfl_xor(pd, 1); ps += __shfl_xor(ps, 1);
        pd += __shfl_xor(pd, 2); ps += __shfl_xor(ps, 2);
        pd += __shfl_xor(pd, 4); ps += __shfl_xor(ps, 4);
        pd += __shfl_xor(pd, 8); ps += __shfl_xor(ps, 8);
        if (m == 0) {
            float2* p = (float2*)&g1v4[(size_t)set * NN + node];
            *p = make_float2(ps, pd);   // .x=ps, .y=pd
        }
    }
}

// ---------- bucket phase B: LDS cursors + fused gate -> 4B CSR recs (localized writes) ----------
__global__ __launch_bounds__(256) void k_bucketB(const int* __restrict__ gcur,
                                                 const unsigned int* __restrict__ tmp,
                                                 const int* __restrict__ rowptr,
                                                 const float4* __restrict__ g1v4,
                                                 const float* __restrict__ fw,
                                                 unsigned int* __restrict__ csr) {
    int b = blockIdx.x, set = blockIdx.y;
    int nb = b * BW;
    if (nb >= NN) return;
    __shared__ float4 gdw[BW];
    __shared__ int cur[BW];
    __shared__ int rpl[BW];
    int tid = threadIdx.x;
    int nv = NN - nb < BW ? NN - nb : BW;
    if (tid < nv) {
        gdw[tid] = g1v4[(size_t)set * NN + nb + tid];
        rpl[tid] = rowptr[(size_t)set * NN + nb + tid];
        cur[tid] = 0;
    }
    __syncthreads();
    int cnt = gcur[set * NB + b];
    if (cnt > CAP) cnt = CAP;
    float gbv = fw[OFF_GB1 + set];
    const float4* gv = g1v4 + (size_t)set * NN;
    const unsigned int* tp = tmp + (size_t)set * NB * CAP + (size_t)b * CAP;
    unsigned int* cp = csr + (size_t)set * NB * CAP;
    for (int j = tid; j < cnt; j += 256) {
        unsigned rec = tp[j];
        int s = rec & 0xFFFF;
        int dl = rec >> 16;
        float4 gs = gv[s];
        float4 gd = gdw[dl];
        float a = tanh_fast(gd.y + gs.x + gbv);
        float e = a * gd.z * gs.z;
        int rank = atomicAdd(&cur[dl], 1);
        cp[rpl[dl] + rank] = (unsigned)s | ((unsigned)f2bf(e) << 16);
    }
}

// ---------- layer 1: node-parallel aggregate (4B recs) + MFMA hw1 epilogue ----------
__global__ __launch_bounds__(1024) void k_layer1(const unsigned short* __restrict__ x16,
                                                 const unsigned int* __restrict__ csr,
                                                 const int* __restrict__ rowptr,
                                                 const int* __restrict__ deg,
                                                 const unsigned short* __restrict__ wb,
                                                 unsigned short* __restrict__ raw2_16) {
    int set = blockIdx.y;
    __shared__ unsigned short tb[16][72];
    int tid = threadIdx.x, lane = tid & 63, wid = tid >> 6;
    int m = lane & 15, q = lane >> 4;
    int node = blockIdx.x * 16 + wid;
    int start = rfl(rowptr[(size_t)set * NN + node]);
    int cnt = rfl(deg[(size_t)set * NN + node]);
    const unsigned int* cs = csr + (size_t)set * NB * CAP + start;
    float acc = 0.f;
    int j = 0;
    for (; j + 4 <= cnt; j += 4) {
        unsigned r0 = cs[j], r1 = cs[j + 1], r2 = cs[j + 2], r3 = cs[j + 3];
        float v0 = bf2f(x16[(size_t)(r0 & 0xFFFF) * 64 + lane]);
        float v1 = bf2f(x16[(size_t)(r1 & 0xFFFF) * 64 + lane]);
        float v2 = bf2f(x16[(size_t)(r2 & 0xFFFF) * 64 + lane]);
        float v3 = bf2f(x16[(size_t)(r3 & 0xFFFF) * 64 + lane]);
        acc = fmaf(v0, bf2f((unsigned short)(r0 >> 16)), acc);
        acc = fmaf(v1, bf2f((unsigned short)(r1 >> 16)), acc);
        acc = fmaf(v2, bf2f((unsigned short)(r2 >> 16)), acc);
        acc = fmaf(v3, bf2f((unsigned short)(r3 >> 16)), acc);
    }
    for (; j < cnt; ++j) {
        unsigned r0 = cs[j];
        acc = fmaf(bf2f(x16[(size_t)(r0 & 0xFFFF) * 64 + lane]), bf2f((unsigned short)(r0 >> 16)), acc);
    }
    float t = fmaf(0.3f, bf2f(x16[(size_t)node * 64 + lane]), acc);
    tb[wid][lane] = f2bf(t);
    __syncthreads();
    if (wid < 4) {
        f32x4 c = {0.f, 0.f, 0.f, 0.f};
        const unsigned short* bp = wb + WB_HW1T + set * 4096 + (wid * 16 + m) * 64 + q * 8;
#pragma unroll
        for (int k0 = 0; k0 < 64; k0 += 32) {
            bf16x8 a = *(const bf16x8*)&tb[m][k0 + q * 8];
            bf16x8 b = *(const bf16x8*)(bp + k0);
            c = __builtin_amdgcn_mfma_f32_16x16x32_bf16(a, b, c, 0, 0, 0);
        }
        int gcol = wid * 16 + m;
#pragma unroll
        for (int r = 0; r < 4; ++r) {
            int row = q * 4 + r;
            raw2_16[(size_t)(blockIdx.x * 16 + row) * 192 + set * 64 + gcol] = f2bf(leakyf(c[r]));
        }
    }
}

// ---------- layer-2 gate scalars from raw2 ----------
__global__ __launch_bounds__(1024) void k_p2(const unsigned short* __restrict__ raw2_16,
                                             const float* __restrict__ fw,
                                             float4* __restrict__ g2v4) {
    int tid = threadIdx.x, lane = tid & 63, wid = tid >> 6;
    int node = blockIdx.x * 16 + wid;
    const unsigned short* r = raw2_16 + (size_t)node * 192;
    float v0 = bf2f(r[lane]);
    float v1 = bf2f(r[64 + lane]);
    float v2 = bf2f(r[128 + lane]);
#pragma unroll
    for (int k = 0; k < 3; ++k) {
        const float* g = fw + OFF_GW2 + k * 384;
        float pd = v0 * g[lane] + v1 * g[64 + lane] + v2 * g[128 + lane];
        float ps = v0 * g[192 + lane] + v1 * g[256 + lane] + v2 * g[320 + lane];
#pragma unroll
        for (int mm = 32; mm >= 1; mm >>= 1) { pd += __shfl_xor(pd, mm); ps += __shfl_xor(ps, mm); }
        if (lane == 0) {
            float2* p = (float2*)&g2v4[(size_t)k * NN + node];
            *p = make_float2(ps, pd);
        }
    }
}

// ---------- mark batch nodes, assign compact slots, build slot->node list ----------
__global__ __launch_bounds__(256) void k_mark(const int* __restrict__ nodes, int* __restrict__ mark,
                                              int* __restrict__ slotof, int* __restrict__ slotnode,
                                              int* __restrict__ cnt) {
    int b = blockIdx.x * 256 + threadIdx.x;
    if (b < BB) {
        int n = nodes[b];
        if (atomicCAS(&mark[n], 0, 1) == 0) {
            int s = atomicAdd(cnt, 1);
            slotof[n] = s;
            slotnode[s] = n;
        }
    }
}

// ---------- layer 2 aggregation over compact slot list, inline gate ----------
__global__ __launch_bounds__(1024) void k_layer2(const unsigned short* __restrict__ raw2_16,
                                                 const unsigned int* __restrict__ csr,
                                                 const int* __restrict__ rowptr,
                                                 const int* __restrict__ deg,
                                                 const float4* __restrict__ g2v4,
                                                 const float* __restrict__ fw,
                                                 const int* __restrict__ slotnode,
                                                 const int* __restrict__ cntp,
                                                 float* __restrict__ z2) {
    int set = blockIdx.y;
    int tid = threadIdx.x, lane = tid & 63, wid = tid >> 6;
    int slot = blockIdx.x * 16 + wid;
    if (slot >= cntp[0]) return;
    int node = rfl(slotnode[slot]);
    int start = rfl(rowptr[(size_t)set * NN + node]);
    int cnt = rfl(deg[(size_t)set * NN + node]);
    float4 gn = g2v4[(size_t)set * NN + node];
    float pdv = gn.y, dnd = gn.z;
    float gbv = fw[OFF_GB2 + set];
    const unsigned int* cs = csr + (size_t)set * NB * CAP + start;
    const float4* gv = g2v4 + (size_t)set * NN;
    float a0 = 0.f, a1 = 0.f, a2 = 0.f;
    for (int j = 0; j < cnt; ++j) {
        unsigned rec = cs[j];
        int s = rec & 0xFFFF;
        float4 g = gv[s];
        float a = tanh_fast(pdv + g.x + gbv);
        float e = a * dnd * g.z;
        const unsigned short* r = raw2_16 + (size_t)s * 192;
        a0 = fmaf(bf2f(r[lane]), e, a0);
        a1 = fmaf(bf2f(r[64 + lane]), e, a1);
        a2 = fmaf(bf2f(r[128 + lane]), e, a2);
    }
    float* z = z2 + (size_t)slot * 576 + (size_t)set * 192;
    z[lane] = a0; z[64 + lane] = a1; z[128 + lane] = a2;
}

// ---------- final: 16 rows/block, MFMA hw2 + t2 GEMMs, t3 epilogue ----------
__global__ __launch_bounds__(256) void k_final(const int* __restrict__ fl,
                                               const int* __restrict__ nodes,
                                               const int* __restrict__ slotof,
                                               const float* __restrict__ z2,
                                               const unsigned short* __restrict__ raw2_16,
                                               const unsigned short* __restrict__ x16,
                                               const void* __restrict__ hB,
                                               const float* __restrict__ fw,
                                               const unsigned short* __restrict__ wb,
                                               void* __restrict__ outv) {
    __shared__ unsigned short nfb[16][712];
    __shared__ unsigned short tbb[16][200];
    __shared__ float sarr[16][64];
    __shared__ int nd[16], sl[16];
    int tid = threadIdx.x, lane = tid & 63, wid = tid >> 6;
    int m = lane & 15, q = lane >> 4;
    int b0 = blockIdx.x * 16;
    int isf32 = fl[0];
    if (tid < 16) {
        int n = nodes[b0 + tid];
        nd[tid] = n;
        sl[tid] = slotof[n];
    }
    __syncthreads();
    for (int idx = tid; idx < 16 * 256; idx += 256) {
        int row = idx >> 8, c = idx & 255;
        size_t hi = (size_t)nd[row] * 256 + c;
        nfb[row][192 + c] = isf32 ? f2bf(((const float*)hB)[hi]) : ((const unsigned short*)hB)[hi];
    }
    for (int idx = tid; idx < 16 * 64; idx += 256) {
        int row = idx >> 6, c = idx & 63;
        nfb[row][448 + c] = x16[(size_t)nd[row] * 64 + c];
    }
    for (int idx = tid; idx < 16 * 192; idx += 256) {
        int row = idx / 192, c = idx % 192;
        nfb[row][512 + c] = raw2_16[(size_t)nd[row] * 192 + c];
    }
    for (int set = 0; set < 3; ++set) {
        __syncthreads();
        for (int idx = tid; idx < 16 * 192; idx += 256) {
            int row = idx / 192, c = idx % 192;
            float r2 = bf2f(nfb[row][512 + c]);
            tbb[row][c] = f2bf(fmaf(0.3f, r2, z2[(size_t)sl[row] * 576 + set * 192 + c]));
        }
        __syncthreads();
        f32x4 c4 = {0.f, 0.f, 0.f, 0.f};
        const unsigned short* bp = wb + WB_HW2T + set * 12288 + (wid * 16 + m) * 192 + q * 8;
#pragma unroll
        for (int k0 = 0; k0 < 192; k0 += 32) {
            bf16x8 a = *(const bf16x8*)&tbb[m][k0 + q * 8];
            bf16x8 bf = *(const bf16x8*)(bp + k0);
            c4 = __builtin_amdgcn_mfma_f32_16x16x32_bf16(a, bf, c4, 0, 0, 0);
        }
        int col = wid * 16 + m;
#pragma unroll
        for (int r = 0; r < 4; ++r)
            nfb[q * 4 + r][set * 64 + col] = f2bf(leakyf(c4[r]));
    }
    __syncthreads();
    f32x4 c4 = {0.f, 0.f, 0.f, 0.f};
    const unsigned short* bp = wb + WB_T2W + (wid * 16 + m) * 704 + q * 8;
#pragma unroll
    for (int k0 = 0; k0 < 704; k0 += 32) {
        bf16x8 a = *(const bf16x8*)&nfb[m][k0 + q * 8];
        bf16x8 bf = *(const bf16x8*)(bp + k0);
        c4 = __builtin_amdgcn_mfma_f32_16x16x32_bf16(a, bf, c4, 0, 0, 0);
    }
    int col = wid * 16 + m;
    float bias = fw[OFF_T2B + col];
#pragma unroll
    for (int r = 0; r < 4; ++r) {
        int row = q * 4 + r;
        float sv = leakyf(c4[r] + bias);
        sarr[row][col] = sv;
        size_t oi = 8192 + (size_t)(b0 + row) * 64 + col;
        if (isf32) ((float*)outv)[oi] = sv;
        else ((unsigned short*)outv)[oi] = f2bf(sv);
    }
    __syncthreads();
    if (tid < 32) {
        int row = tid >> 1, oc = tid & 1;
        float acc2 = fw[OFF_T3B + oc];
        const float* tw = fw + OFF_T3W + oc * 64;
#pragma unroll 8
        for (int c = 0; c < 64; ++c) acc2 = fmaf(sarr[row][c], tw[c], acc2);
        size_t oi = (size_t)(b0 + row) * 2 + oc;
        if (isf32) ((float*)outv)[oi] = acc2;
        else ((unsigned short*)outv)[oi] = f2bf(acc2);
    }
}

extern "C" void kernel_launch(void* const* d_in, const int* in_sizes, int n_in,
                              void* d_out, int out_size, void* d_ws, size_t ws_size,
                              hipStream_t stream) {
    const void* h = d_in[0];
    const int* src1 = (const int*)d_in[1];
    const int* dst1 = (const int*)d_in[2];
    const int* src2 = (const int*)d_in[3];
    const int* dst2 = (const int*)d_in[4];
    const int* src3 = (const int*)d_in[5];
    const int* dst3 = (const int*)d_in[6];
    const int* nodes = (const int*)d_in[7];

    char* w = (char*)d_ws;
    size_t off = 0;
    auto carve = [&](size_t bytes) -> void* {
        void* p = w + off;
        off += (bytes + 255) & ~(size_t)255;
        return p;
    };
    int* flag = (int*)carve(256);
    int* gcur = (int*)carve((size_t)3 * NB * 4);       // zeroed
    int* mark = (int*)carve((size_t)NN * 4);           // zeroed
    int* cntp = (int*)carve(256);                      // zeroed
    int* deg = (int*)carve((size_t)3 * NN * 4);
    int* rowptr = (int*)carve((size_t)3 * NN * 4);
    float4* g1v4 = (float4*)carve((size_t)3 * NN * 16);
    float4* g2v4 = (float4*)carve((size_t)3 * NN * 16);
    unsigned int* tmp = (unsigned int*)carve((size_t)3 * NB * CAP * 4);
    unsigned int* csr = (unsigned int*)carve((size_t)3 * NB * CAP * 4);
    float* fw = (float*)carve((size_t)WTOT * 4);
    unsigned short* wb = (unsigned short*)carve((size_t)WB_TOT * 2);
    unsigned short* x16 = (unsigned short*)carve((size_t)NN * 64 * 2);
    unsigned short* raw2_16 = (unsigned short*)carve((size_t)NN * 192 * 2);
    int* slotof = (int*)carve((size_t)NN * 4);
    int* slotnode = (int*)carve((size_t)BB * 4);
    float* z2 = (float*)carve((size_t)BB * 576 * 4);

    size_t zbytes = (size_t)((char*)cntp - (char*)gcur) + 256;
    hipMemsetAsync(gcur, 0, zbytes, stream);

    k_sniff<<<1, 64, 0, stream>>>((const unsigned short*)h, flag);
    k_convert<<<(WTOT + 1023) / 1024, 1024, 0, stream>>>(
        flag, d_in[8], d_in[9],
        d_in[10], d_in[16], d_in[22],
        d_in[11], d_in[17], d_in[23],
        d_in[12], d_in[18], d_in[24],
        d_in[13], d_in[19], d_in[25],
        d_in[14], d_in[20], d_in[26],
        d_in[15], d_in[21], d_in[27],
        d_in[28], d_in[29], d_in[30], d_in[31], fw);
    k_convert16<<<(WB_TOT + 255) / 256, 256, 0, stream>>>(flag, d_in[8],
                                                          d_in[12], d_in[18], d_in[24],
                                                          d_in[15], d_in[21], d_in[27],
                                                          d_in[28], wb);

    dim3 gch(CH, 3);
    k_bucketA<<<gch, 256, 0, stream>>>(src1, src2, src3, dst1, dst2, dst3, gcur, tmp);
    dim3 gb(NB, 3);
    k_rowptr<<<gb, 256, 0, stream>>>(gcur, tmp, deg, rowptr, (float*)g1v4, (float*)g2v4);

    k_input<<<3125, 256, 0, stream>>>(flag, h, wb, fw, x16, g1v4);
    k_bucketB<<<gb, 256, 0, stream>>>(gcur, tmp, rowptr, g1v4, fw, csr);

    dim3 gl(3125, 3);
    k_layer1<<<gl, 1024, 0, stream>>>(x16, csr, rowptr, deg, wb, raw2_16);
    k_p2<<<3125, 1024, 0, stream>>>(raw2_16, fw, g2v4);
    k_mark<<<(BB + 255) / 256, 256, 0, stream>>>(nodes, mark, slotof, slotnode, cntp);
    dim3 gl2(BB / 16, 3);
    k_layer2<<<gl2, 1024, 0, stream>>>(raw2_16, csr, rowptr, deg, g2v4, fw, slotnode, cntp, z2);
    k_final<<<BB / 16, 256, 0, stream>>>(flag, nodes, slotof, z2, raw2_16, x16, h, fw, wb, d_out);
}

// Round 8
// 413.636 us; speedup vs baseline: 3.7252x; 1.0449x over previous
//
#include <hip/hip_runtime.h>

#define NN 50000
#define EE 800000
#define BB 4096
#define NB 512       // dst buckets
#define BW 98        // nodes per bucket
#define CAP 2176     // slot capacity per bucket (mean 1568 + ~15 sigma)
#define CH 128       // edge chunks per set in bucketA

// f32 weight-table offsets (elements)
#define OFF_T1W 0
#define OFF_T1B 16384
#define OFF_GW1 16448
#define OFF_GB1 16832
#define OFF_HW1 16848
#define OFF_GW2 29136
#define OFF_GB2 30288
#define OFF_HW2 30304
#define OFF_T2W 67168
#define OFF_T2B 112224
#define OFF_T3W 112288
#define OFF_T3B 112416
#define WTOT    112418

// bf16 weight table (MFMA B-operands)
#define WB_T1W  0        // t1w native [64][256]
#define WB_HW1T 16384    // 3 x hw1^T [64][64]
#define WB_HW2T 28672    // 3 x hw2^T [64][192]
#define WB_T2W  65536    // t2w native [64][704]
#define WB_TOT  110592

typedef __attribute__((ext_vector_type(8))) short bf16x8;
typedef __attribute__((ext_vector_type(4))) float f32x4;

__device__ __forceinline__ float bf2f(unsigned short u) {
    return __uint_as_float(((unsigned int)u) << 16);
}
__device__ __forceinline__ unsigned short f2bf(float f) {
    unsigned int u = __float_as_uint(f);
    u = (u + 0x7fffu + ((u >> 16) & 1u)) >> 16;
    return (unsigned short)u;
}
__device__ __forceinline__ float leakyf(float v) { return v >= 0.f ? v : 0.3f * v; }
__device__ __forceinline__ float tanh_fast(float v) {
    float e = __expf(2.f * v);
    return 1.f - 2.f / (e + 1.f);
}
__device__ __forceinline__ int rfl(int v) { return __builtin_amdgcn_readfirstlane(v); }

// ---------- dtype sniffer: 0 = bf16, 1 = f32 ----------
__global__ void k_sniff(const unsigned short* __restrict__ hs, int* __restrict__ flag) {
    int lane = threadIdx.x;
    unsigned short s = hs[2 * lane];
    int ef = (s >> 7) & 0xFF;
    unsigned long long m = __ballot(ef >= 100 && ef <= 132);
    if (lane == 0) flag[0] = (__popcll(m) >= 40) ? 0 : 1;
}

// ---------- convert all weight tensors to one f32 table ----------
__global__ __launch_bounds__(1024) void k_convert(
    const int* __restrict__ fl,
    const void* t1w, const void* t1b,
    const void* gw1a, const void* gw1b, const void* gw1c,
    const void* gb1a, const void* gb1b, const void* gb1c,
    const void* hw1a, const void* hw1b, const void* hw1c,
    const void* gw2a, const void* gw2b, const void* gw2c,
    const void* gb2a, const void* gb2b, const void* gb2c,
    const void* hw2a, const void* hw2b, const void* hw2c,
    const void* t2w, const void* t2b, const void* t3w, const void* t3b,
    float* __restrict__ fw) {
    const int starts[24] = {0, 16384, 16448, 16576, 16704, 16832, 16833, 16834,
                            16848, 20944, 25040, 29136, 29520, 29904, 30288, 30289, 30290,
                            30304, 42592, 54880, 67168, 112224, 112288, 112416};
    const int cnts[24] = {16384, 64, 128, 128, 128, 1, 1, 1, 4096, 4096, 4096,
                          384, 384, 384, 1, 1, 1, 12288, 12288, 12288, 45056, 64, 128, 2};
    const void* sp[24] = {t1w, t1b, gw1a, gw1b, gw1c, gb1a, gb1b, gb1c, hw1a, hw1b, hw1c,
                          gw2a, gw2b, gw2c, gb2a, gb2b, gb2c, hw2a, hw2b, hw2c, t2w, t2b, t3w, t3b};
    int isf32 = fl[0];
    int idx = blockIdx.x * 1024 + threadIdx.x;
    if (idx >= WTOT) return;
    float v = 0.f;
#pragma unroll
    for (int k = 0; k < 24; ++k) {
        int lo = idx - starts[k];
        if (lo >= 0 && lo < cnts[k])
            v = isf32 ? ((const float*)sp[k])[lo] : bf2f(((const unsigned short*)sp[k])[lo]);
    }
    fw[idx] = v;
}

// ---------- bf16 weight table: t1w, hw1^T, hw2^T, t2w ----------
__global__ __launch_bounds__(256) void k_convert16(const int* __restrict__ fl, const void* t1w,
                                                   const void* hw1a, const void* hw1b, const void* hw1c,
                                                   const void* hw2a, const void* hw2b, const void* hw2c,
                                                   const void* t2w, unsigned short* __restrict__ wb) {
    int idx = blockIdx.x * 256 + threadIdx.x;
    if (idx >= WB_TOT) return;
    int isf32 = fl[0];
    const void* p;
    int srci;
    if (idx < WB_HW1T) {
        p = t1w; srci = idx;
    } else if (idx < WB_HW2T) {
        int rel = idx - WB_HW1T;
        int set = rel >> 12, r2 = rel & 4095;
        int jj = r2 >> 6, kk = r2 & 63;
        p = set == 0 ? hw1a : (set == 1 ? hw1b : hw1c);
        srci = kk * 64 + jj;
    } else if (idx < WB_T2W) {
        int rel = idx - WB_HW2T;
        int set = rel / 12288, r2 = rel % 12288;
        int n = r2 / 192, k = r2 % 192;
        p = set == 0 ? hw2a : (set == 1 ? hw2b : hw2c);
        srci = k * 64 + n;
    } else {
        p = t2w; srci = idx - WB_T2W;
    }
    wb[idx] = isf32 ? f2bf(((const float*)p)[srci]) : ((const unsigned short*)p)[srci];
}

// ---------- multi-split bucket scatter: two-pass LDS histogram, slot-capped buckets ----------
__global__ __launch_bounds__(256) void k_bucketA(const int* __restrict__ s0, const int* __restrict__ s1,
                                                 const int* __restrict__ s2, const int* __restrict__ d0,
                                                 const int* __restrict__ d1, const int* __restrict__ d2,
                                                 int* __restrict__ gcur, unsigned int* __restrict__ tmp) {
    int set = blockIdx.y;
    const int* ss = set == 0 ? s0 : (set == 1 ? s1 : s2);
    const int* dd = set == 0 ? d0 : (set == 1 ? d1 : d2);
    __shared__ int hist[NB];
    __shared__ int lcur[NB];
    int tid = threadIdx.x;
    for (int i = tid; i < NB; i += 256) { hist[i] = 0; lcur[i] = 0; }
    __syncthreads();
    int e0 = blockIdx.x * (EE / CH);
    int e1 = e0 + (EE / CH);
    for (int t = e0 + tid; t < e1; t += 256)
        atomicAdd(&hist[dd[t] / BW], 1);
    __syncthreads();
    for (int b = tid; b < NB; b += 256) {
        int hh = hist[b];
        if (hh > 0) hist[b] = atomicAdd(&gcur[set * NB + b], hh);
    }
    __syncthreads();
    unsigned int* tp = tmp + (size_t)set * NB * CAP;
    for (int t = e0 + tid; t < e1; t += 256) {
        int d = dd[t], s = ss[t];
        int b = d / BW;
        int r = atomicAdd(&lcur[b], 1);
        int pos = hist[b] + r;
        if (pos < CAP) tp[(size_t)b * CAP + pos] = (unsigned)s | ((unsigned)(d - b * BW) << 16);
    }
}

// ---------- per-bucket: node degrees, rowptr (slot-relative), rsqrt d ----------
__global__ __launch_bounds__(256) void k_rowptr(const int* __restrict__ gcur,
                                                const unsigned int* __restrict__ tmp,
                                                int* __restrict__ deg, int* __restrict__ rowptr,
                                                float* __restrict__ g1, float* __restrict__ g2) {
    int b = blockIdx.x, set = blockIdx.y;
    int nb = b * BW;
    if (nb >= NN) return;
    __shared__ int hist[BW];
    __shared__ int rp[BW];
    int tid = threadIdx.x;
    int nv = NN - nb < BW ? NN - nb : BW;
    if (tid < BW) hist[tid] = 0;
    __syncthreads();
    int cnt = gcur[set * NB + b];
    if (cnt > CAP) cnt = CAP;
    const unsigned int* tp = tmp + (size_t)set * NB * CAP + (size_t)b * CAP;
    for (int j = tid; j < cnt; j += 256) atomicAdd(&hist[tp[j] >> 16], 1);
    __syncthreads();
    if (tid == 0) {
        int run = 0;
        for (int i = 0; i < nv; ++i) { rp[i] = run; run += hist[i]; }
    }
    __syncthreads();
    if (tid < nv) {
        int dg = hist[tid];
        size_t n = (size_t)set * NN + nb + tid;
        deg[n] = dg;
        rowptr[n] = b * CAP + rp[tid];
        float v = dg > 0 ? rsqrtf((float)dg) : 0.f;
        g1[n * 4 + 2] = v;
        g2[n * 4 + 2] = v;
    }
}

// ---------- input transform via MFMA: x = leaky(h @ t1w^T + b), fused p1 gate dots ----------
__global__ __launch_bounds__(256) void k_input(const int* __restrict__ fl,
                                               const void* __restrict__ hB,
                                               const unsigned short* __restrict__ wb,
                                               const float* __restrict__ fw,
                                               unsigned short* __restrict__ x16,
                                               float4* __restrict__ g1v4) {
    __shared__ float xt[16][65];
    int tid = threadIdx.x, lane = tid & 63, wid = tid >> 6;
    int m = lane & 15, q = lane >> 4;
    int node0 = blockIdx.x * 16;
    int isf32 = fl[0];
    f32x4 acc = {0.f, 0.f, 0.f, 0.f};
    const unsigned short* bsrc = wb + WB_T1W + ((size_t)(wid * 16 + m)) * 256 + q * 8;
    if (isf32) {
        const float* ap = (const float*)hB + (size_t)(node0 + m) * 256 + q * 8;
        for (int k0 = 0; k0 < 256; k0 += 32) {
            float4 f0 = *(const float4*)(ap + k0);
            float4 f1 = *(const float4*)(ap + k0 + 4);
            bf16x8 a;
            a[0] = (short)f2bf(f0.x); a[1] = (short)f2bf(f0.y);
            a[2] = (short)f2bf(f0.z); a[3] = (short)f2bf(f0.w);
            a[4] = (short)f2bf(f1.x); a[5] = (short)f2bf(f1.y);
            a[6] = (short)f2bf(f1.z); a[7] = (short)f2bf(f1.w);
            bf16x8 b = *(const bf16x8*)(bsrc + k0);
            acc = __builtin_amdgcn_mfma_f32_16x16x32_bf16(a, b, acc, 0, 0, 0);
        }
    } else {
        const unsigned short* ap = (const unsigned short*)hB + (size_t)(node0 + m) * 256 + q * 8;
        for (int k0 = 0; k0 < 256; k0 += 32) {
            bf16x8 a = *(const bf16x8*)(ap + k0);
            bf16x8 b = *(const bf16x8*)(bsrc + k0);
            acc = __builtin_amdgcn_mfma_f32_16x16x32_bf16(a, b, acc, 0, 0, 0);
        }
    }
    int gcol = wid * 16 + m;
    float bias = fw[OFF_T1B + gcol];
#pragma unroll
    for (int r = 0; r < 4; ++r) {
        int row = q * 4 + r;
        float v = leakyf(acc[r] + bias);
        x16[(size_t)(node0 + row) * 64 + gcol] = f2bf(v);
        xt[row][gcol] = v;
    }
    __syncthreads();
    int nl = wid * 4 + q;
    int node = node0 + nl;
    float xv[4];
#pragma unroll
    for (int r = 0; r < 4; ++r) xv[r] = xt[nl][m + 16 * r];
#pragma unroll
    for (int set = 0; set < 3; ++set) {
        const float* gw = fw + OFF_GW1 + set * 128;
        float pd = 0.f, ps = 0.f;
#pragma unroll
        for (int r = 0; r < 4; ++r) {
            int c = m + 16 * r;
            pd = fmaf(xv[r], gw[c], pd);
            ps = fmaf(xv[r], gw[64 + c], ps);
        }
        pd += __shfl_xor(pd, 1); ps += __shfl_xor(ps, 1);
        pd += __shfl_xor(pd, 2); ps += __shfl_xor(ps, 2);
        pd += __shfl_xor(pd, 4); ps += __shfl_xor(ps, 4);
        pd += __shfl_xor(pd, 8); ps += __shfl_xor(ps, 8);
        if (m == 0) {
            float2* p = (float2*)&g1v4[(size_t)set * NN + node];
            *p = make_float2(ps, pd);   // .x=ps, .y=pd
        }
    }
}

// ---------- bucket phase B: LDS cursors + fused gate -> 4B CSR recs (localized writes) ----------
__global__ __launch_bounds__(256) void k_bucketB(const int* __restrict__ gcur,
                                                 const unsigned int* __restrict__ tmp,
                                                 const int* __restrict__ rowptr,
                                                 const float4* __restrict__ g1v4,
                                                 const float* __restrict__ fw,
                                                 unsigned int* __restrict__ csr) {
    int b = blockIdx.x, set = blockIdx.y;
    int nb = b * BW;
    if (nb >= NN) return;
    __shared__ float4 gdw[BW];
    __shared__ int cur[BW];
    __shared__ int rpl[BW];
    int tid = threadIdx.x;
    int nv = NN - nb < BW ? NN - nb : BW;
    if (tid < nv) {
        gdw[tid] = g1v4[(size_t)set * NN + nb + tid];
        rpl[tid] = rowptr[(size_t)set * NN + nb + tid];
        cur[tid] = 0;
    }
    __syncthreads();
    int cnt = gcur[set * NB + b];
    if (cnt > CAP) cnt = CAP;
    float gbv = fw[OFF_GB1 + set];
    const float4* gv = g1v4 + (size_t)set * NN;
    const unsigned int* tp = tmp + (size_t)set * NB * CAP + (size_t)b * CAP;
    unsigned int* cp = csr + (size_t)set * NB * CAP;
    for (int j = tid; j < cnt; j += 256) {
        unsigned rec = tp[j];
        int s = rec & 0xFFFF;
        int dl = rec >> 16;
        float4 gs = gv[s];
        float4 gd = gdw[dl];
        float a = tanh_fast(gd.y + gs.x + gbv);
        float e = a * gd.z * gs.z;
        int rank = atomicAdd(&cur[dl], 1);
        cp[rpl[dl] + rank] = (unsigned)s | ((unsigned)f2bf(e) << 16);
    }
}

// ---------- fused layer 1 + p2: split-wave gathers, all 3 sets per block, MFMA epilogue ----------
__global__ __launch_bounds__(1024) void k_layer1(const unsigned short* __restrict__ x16,
                                                 const unsigned int* __restrict__ csr,
                                                 const int* __restrict__ rowptr,
                                                 const int* __restrict__ deg,
                                                 const float* __restrict__ fw,
                                                 const unsigned short* __restrict__ wb,
                                                 unsigned short* __restrict__ raw2_16,
                                                 float4* __restrict__ g2v4) {
    __shared__ unsigned short tb[3][16][72];   // t vectors per set (MFMA A rows)
    __shared__ unsigned short r2l[16][200];    // raw2 of 16 nodes (192 + pad)
    int tid = threadIdx.x, lane = tid & 63, wid = tid >> 6;
    int half = lane >> 5, c = lane & 31;
    int node = blockIdx.x * 16 + wid;
    unsigned xres = *(const unsigned*)(x16 + (size_t)node * 64 + 2 * c);
    float xr0 = bf2f((unsigned short)(xres & 0xFFFF));
    float xr1 = bf2f((unsigned short)(xres >> 16));
#pragma unroll
    for (int set = 0; set < 3; ++set) {
        int start = rfl(rowptr[(size_t)set * NN + node]);
        int cnt = rfl(deg[(size_t)set * NN + node]);
        const unsigned int* cs = csr + (size_t)set * NB * CAP + start;
        float a0 = 0.f, a1 = 0.f;
        int j = 0;
        for (; j + 8 <= cnt; j += 8) {
#pragma unroll
            for (int k = 0; k < 4; ++k) {
                unsigned rec = cs[j + 2 * k + half];
                float e = bf2f((unsigned short)(rec >> 16));
                unsigned u = *(const unsigned*)(x16 + (size_t)(rec & 0xFFFF) * 64 + 2 * c);
                a0 = fmaf(bf2f((unsigned short)(u & 0xFFFF)), e, a0);
                a1 = fmaf(bf2f((unsigned short)(u >> 16)), e, a1);
            }
        }
        for (; j + 2 <= cnt; j += 2) {
            unsigned rec = cs[j + half];
            float e = bf2f((unsigned short)(rec >> 16));
            unsigned u = *(const unsigned*)(x16 + (size_t)(rec & 0xFFFF) * 64 + 2 * c);
            a0 = fmaf(bf2f((unsigned short)(u & 0xFFFF)), e, a0);
            a1 = fmaf(bf2f((unsigned short)(u >> 16)), e, a1);
        }
        if (j < cnt && half == 0) {
            unsigned rec = cs[j];
            float e = bf2f((unsigned short)(rec >> 16));
            unsigned u = *(const unsigned*)(x16 + (size_t)(rec & 0xFFFF) * 64 + 2 * c);
            a0 = fmaf(bf2f((unsigned short)(u & 0xFFFF)), e, a0);
            a1 = fmaf(bf2f((unsigned short)(u >> 16)), e, a1);
        }
        a0 += __shfl_xor(a0, 32);
        a1 += __shfl_xor(a1, 32);
        if (half == 0) {
            unsigned p = ((unsigned)f2bf(fmaf(0.3f, xr1, a1)) << 16) |
                         (unsigned)f2bf(fmaf(0.3f, xr0, a0));
            *(unsigned*)&tb[set][wid][2 * c] = p;
        }
    }
    __syncthreads();
    int m = lane & 15, q = lane >> 4;
    if (wid < 12) {
        int set = wid >> 2, sw = wid & 3;
        f32x4 c4 = {0.f, 0.f, 0.f, 0.f};
        const unsigned short* bp = wb + WB_HW1T + set * 4096 + (sw * 16 + m) * 64 + q * 8;
#pragma unroll
        for (int k0 = 0; k0 < 64; k0 += 32) {
            bf16x8 a = *(const bf16x8*)&tb[set][m][k0 + q * 8];
            bf16x8 b = *(const bf16x8*)(bp + k0);
            c4 = __builtin_amdgcn_mfma_f32_16x16x32_bf16(a, b, c4, 0, 0, 0);
        }
        int gcol = sw * 16 + m;
#pragma unroll
        for (int r = 0; r < 4; ++r) {
            int row = q * 4 + r;
            unsigned short v = f2bf(leakyf(c4[r]));
            raw2_16[(size_t)(blockIdx.x * 16 + row) * 192 + set * 64 + gcol] = v;
            r2l[row][set * 64 + gcol] = v;
        }
    }
    __syncthreads();
    // fused p2: wave wid handles node wid; lane covers 3 features each
    float pd[3] = {0.f, 0.f, 0.f}, ps[3] = {0.f, 0.f, 0.f};
    float rv[3];
#pragma unroll
    for (int t = 0; t < 3; ++t) rv[t] = bf2f(r2l[wid][lane * 3 + t]);
#pragma unroll
    for (int set = 0; set < 3; ++set) {
        const float* g = fw + OFF_GW2 + set * 384;
#pragma unroll
        for (int t = 0; t < 3; ++t) {
            int cc = lane * 3 + t;
            pd[set] = fmaf(rv[t], g[cc], pd[set]);
            ps[set] = fmaf(rv[t], g[192 + cc], ps[set]);
        }
    }
#pragma unroll
    for (int mm = 32; mm >= 1; mm >>= 1) {
#pragma unroll
        for (int set = 0; set < 3; ++set) {
            pd[set] += __shfl_xor(pd[set], mm);
            ps[set] += __shfl_xor(ps[set], mm);
        }
    }
    if (lane == 0) {
#pragma unroll
        for (int set = 0; set < 3; ++set) {
            float2* p = (float2*)&g2v4[(size_t)set * NN + node];
            *p = make_float2(ps[set], pd[set]);   // .x=ps, .y=pd (keep .z = d)
        }
    }
}

// ---------- mark batch nodes, assign compact slots, build slot->node list ----------
__global__ __launch_bounds__(256) void k_mark(const int* __restrict__ nodes, int* __restrict__ mark,
                                              int* __restrict__ slotof, int* __restrict__ slotnode,
                                              int* __restrict__ cnt) {
    int b = blockIdx.x * 256 + threadIdx.x;
    if (b < BB) {
        int n = nodes[b];
        if (atomicCAS(&mark[n], 0, 1) == 0) {
            int s = atomicAdd(cnt, 1);
            slotof[n] = s;
            slotnode[s] = n;
        }
    }
}

// ---------- layer 2 aggregation over compact slot list: split-wave gathers, inline gate ----------
__global__ __launch_bounds__(1024) void k_layer2(const unsigned short* __restrict__ raw2_16,
                                                 const unsigned int* __restrict__ csr,
                                                 const int* __restrict__ rowptr,
                                                 const int* __restrict__ deg,
                                                 const float4* __restrict__ g2v4,
                                                 const float* __restrict__ fw,
                                                 const int* __restrict__ slotnode,
                                                 const int* __restrict__ cntp,
                                                 float* __restrict__ z2) {
    int set = blockIdx.y;
    int tid = threadIdx.x, lane = tid & 63, wid = tid >> 6;
    int half = lane >> 5, c = lane & 31;
    int slot = blockIdx.x * 16 + wid;
    if (slot >= cntp[0]) return;
    int node = rfl(slotnode[slot]);
    int start = rfl(rowptr[(size_t)set * NN + node]);
    int cnt = rfl(deg[(size_t)set * NN + node]);
    float4 gn = g2v4[(size_t)set * NN + node];
    float pdv = gn.y, dnd = gn.z;
    float gbv = fw[OFF_GB2 + set];
    const unsigned int* cs = csr + (size_t)set * NB * CAP + start;
    const float4* gv = g2v4 + (size_t)set * NN;
    float a[6] = {0.f, 0.f, 0.f, 0.f, 0.f, 0.f};
    int j = 0;
    for (; j + 2 <= cnt; j += 2) {
        unsigned rec = cs[j + half];
        int s = rec & 0xFFFF;
        float4 g = gv[s];
        float e = tanh_fast(pdv + g.x + gbv) * dnd * g.z;
        const unsigned short* r = raw2_16 + (size_t)s * 192;
#pragma unroll
        for (int blk = 0; blk < 3; ++blk) {
            unsigned u = *(const unsigned*)(r + blk * 64 + 2 * c);
            a[2 * blk] = fmaf(bf2f((unsigned short)(u & 0xFFFF)), e, a[2 * blk]);
            a[2 * blk + 1] = fmaf(bf2f((unsigned short)(u >> 16)), e, a[2 * blk + 1]);
        }
    }
    if (j < cnt && half == 0) {
        unsigned rec = cs[j];
        int s = rec & 0xFFFF;
        float4 g = gv[s];
        float e = tanh_fast(pdv + g.x + gbv) * dnd * g.z;
        const unsigned short* r = raw2_16 + (size_t)s * 192;
#pragma unroll
        for (int blk = 0; blk < 3; ++blk) {
            unsigned u = *(const unsigned*)(r + blk * 64 + 2 * c);
            a[2 * blk] = fmaf(bf2f((unsigned short)(u & 0xFFFF)), e, a[2 * blk]);
            a[2 * blk + 1] = fmaf(bf2f((unsigned short)(u >> 16)), e, a[2 * blk + 1]);
        }
    }
#pragma unroll
    for (int i = 0; i < 6; ++i) a[i] += __shfl_xor(a[i], 32);
    if (half == 0) {
        float* z = z2 + (size_t)slot * 576 + (size_t)set * 192;
#pragma unroll
        for (int blk = 0; blk < 3; ++blk) {
            z[blk * 64 + 2 * c] = a[2 * blk];
            z[blk * 64 + 2 * c + 1] = a[2 * blk + 1];
        }
    }
}

// ---------- final: 16 rows/block, MFMA hw2 + t2 GEMMs, t3 epilogue ----------
__global__ __launch_bounds__(256) void k_final(const int* __restrict__ fl,
                                               const int* __restrict__ nodes,
                                               const int* __restrict__ slotof,
                                               const float* __restrict__ z2,
                                               const unsigned short* __restrict__ raw2_16,
                                               const unsigned short* __restrict__ x16,
                                               const void* __restrict__ hB,
                                               const float* __restrict__ fw,
                                               const unsigned short* __restrict__ wb,
                                               void* __restrict__ outv) {
    __shared__ unsigned short nfb[16][712];
    __shared__ unsigned short tbb[16][200];
    __shared__ float sarr[16][64];
    __shared__ int nd[16], sl[16];
    int tid = threadIdx.x, lane = tid & 63, wid = tid >> 6;
    int m = lane & 15, q = lane >> 4;
    int b0 = blockIdx.x * 16;
    int isf32 = fl[0];
    if (tid < 16) {
        int n = nodes[b0 + tid];
        nd[tid] = n;
        sl[tid] = slotof[n];
    }
    __syncthreads();
    for (int idx = tid; idx < 16 * 256; idx += 256) {
        int row = idx >> 8, c = idx & 255;
        size_t hi = (size_t)nd[row] * 256 + c;
        nfb[row][192 + c] = isf32 ? f2bf(((const float*)hB)[hi]) : ((const unsigned short*)hB)[hi];
    }
    for (int idx = tid; idx < 16 * 64; idx += 256) {
        int row = idx >> 6, c = idx & 63;
        nfb[row][448 + c] = x16[(size_t)nd[row] * 64 + c];
    }
    for (int idx = tid; idx < 16 * 192; idx += 256) {
        int row = idx / 192, c = idx % 192;
        nfb[row][512 + c] = raw2_16[(size_t)nd[row] * 192 + c];
    }
    for (int set = 0; set < 3; ++set) {
        __syncthreads();
        for (int idx = tid; idx < 16 * 192; idx += 256) {
            int row = idx / 192, c = idx % 192;
            float r2 = bf2f(nfb[row][512 + c]);
            tbb[row][c] = f2bf(fmaf(0.3f, r2, z2[(size_t)sl[row] * 576 + set * 192 + c]));
        }
        __syncthreads();
        f32x4 c4 = {0.f, 0.f, 0.f, 0.f};
        const unsigned short* bp = wb + WB_HW2T + set * 12288 + (wid * 16 + m) * 192 + q * 8;
#pragma unroll
        for (int k0 = 0; k0 < 192; k0 += 32) {
            bf16x8 a = *(const bf16x8*)&tbb[m][k0 + q * 8];
            bf16x8 bf = *(const bf16x8*)(bp + k0);
            c4 = __builtin_amdgcn_mfma_f32_16x16x32_bf16(a, bf, c4, 0, 0, 0);
        }
        int col = wid * 16 + m;
#pragma unroll
        for (int r = 0; r < 4; ++r)
            nfb[q * 4 + r][set * 64 + col] = f2bf(leakyf(c4[r]));
    }
    __syncthreads();
    f32x4 c4 = {0.f, 0.f, 0.f, 0.f};
    const unsigned short* bp = wb + WB_T2W + (wid * 16 + m) * 704 + q * 8;
#pragma unroll
    for (int k0 = 0; k0 < 704; k0 += 32) {
        bf16x8 a = *(const bf16x8*)&nfb[m][k0 + q * 8];
        bf16x8 bf = *(const bf16x8*)(bp + k0);
        c4 = __builtin_amdgcn_mfma_f32_16x16x32_bf16(a, bf, c4, 0, 0, 0);
    }
    int col = wid * 16 + m;
    float bias = fw[OFF_T2B + col];
#pragma unroll
    for (int r = 0; r < 4; ++r) {
        int row = q * 4 + r;
        float sv = leakyf(c4[r] + bias);
        sarr[row][col] = sv;
        size_t oi = 8192 + (size_t)(b0 + row) * 64 + col;
        if (isf32) ((float*)outv)[oi] = sv;
        else ((unsigned short*)outv)[oi] = f2bf(sv);
    }
    __syncthreads();
    if (tid < 32) {
        int row = tid >> 1, oc = tid & 1;
        float acc2 = fw[OFF_T3B + oc];
        const float* tw = fw + OFF_T3W + oc * 64;
#pragma unroll 8
        for (int c = 0; c < 64; ++c) acc2 = fmaf(sarr[row][c], tw[c], acc2);
        size_t oi = (size_t)(b0 + row) * 2 + oc;
        if (isf32) ((float*)outv)[oi] = acc2;
        else ((unsigned short*)outv)[oi] = f2bf(acc2);
    }
}

extern "C" void kernel_launch(void* const* d_in, const int* in_sizes, int n_in,
                              void* d_out, int out_size, void* d_ws, size_t ws_size,
                              hipStream_t stream) {
    const void* h = d_in[0];
    const int* src1 = (const int*)d_in[1];
    const int* dst1 = (const int*)d_in[2];
    const int* src2 = (const int*)d_in[3];
    const int* dst2 = (const int*)d_in[4];
    const int* src3 = (const int*)d_in[5];
    const int* dst3 = (const int*)d_in[6];
    const int* nodes = (const int*)d_in[7];

    char* w = (char*)d_ws;
    size_t off = 0;
    auto carve = [&](size_t bytes) -> void* {
        void* p = w + off;
        off += (bytes + 255) & ~(size_t)255;
        return p;
    };
    int* flag = (int*)carve(256);
    int* gcur = (int*)carve((size_t)3 * NB * 4);       // zeroed
    int* mark = (int*)carve((size_t)NN * 4);           // zeroed
    int* cntp = (int*)carve(256);                      // zeroed
    int* deg = (int*)carve((size_t)3 * NN * 4);
    int* rowptr = (int*)carve((size_t)3 * NN * 4);
    float4* g1v4 = (float4*)carve((size_t)3 * NN * 16);
    float4* g2v4 = (float4*)carve((size_t)3 * NN * 16);
    unsigned int* tmp = (unsigned int*)carve((size_t)3 * NB * CAP * 4);
    unsigned int* csr = (unsigned int*)carve((size_t)3 * NB * CAP * 4);
    float* fw = (float*)carve((size_t)WTOT * 4);
    unsigned short* wb = (unsigned short*)carve((size_t)WB_TOT * 2);
    unsigned short* x16 = (unsigned short*)carve((size_t)NN * 64 * 2);
    unsigned short* raw2_16 = (unsigned short*)carve((size_t)NN * 192 * 2);
    int* slotof = (int*)carve((size_t)NN * 4);
    int* slotnode = (int*)carve((size_t)BB * 4);
    float* z2 = (float*)carve((size_t)BB * 576 * 4);

    size_t zbytes = (size_t)((char*)cntp - (char*)gcur) + 256;
    hipMemsetAsync(gcur, 0, zbytes, stream);

    k_sniff<<<1, 64, 0, stream>>>((const unsigned short*)h, flag);
    k_convert<<<(WTOT + 1023) / 1024, 1024, 0, stream>>>(
        flag, d_in[8], d_in[9],
        d_in[10], d_in[16], d_in[22],
        d_in[11], d_in[17], d_in[23],
        d_in[12], d_in[18], d_in[24],
        d_in[13], d_in[19], d_in[25],
        d_in[14], d_in[20], d_in[26],
        d_in[15], d_in[21], d_in[27],
        d_in[28], d_in[29], d_in[30], d_in[31], fw);
    k_convert16<<<(WB_TOT + 255) / 256, 256, 0, stream>>>(flag, d_in[8],
                                                          d_in[12], d_in[18], d_in[24],
                                                          d_in[15], d_in[21], d_in[27],
                                                          d_in[28], wb);

    dim3 gch(CH, 3);
    k_bucketA<<<gch, 256, 0, stream>>>(src1, src2, src3, dst1, dst2, dst3, gcur, tmp);
    dim3 gb(NB, 3);
    k_rowptr<<<gb, 256, 0, stream>>>(gcur, tmp, deg, rowptr, (float*)g1v4, (float*)g2v4);

    k_input<<<3125, 256, 0, stream>>>(flag, h, wb, fw, x16, g1v4);
    k_bucketB<<<gb, 256, 0, stream>>>(gcur, tmp, rowptr, g1v4, fw, csr);
    k_mark<<<(BB + 255) / 256, 256, 0, stream>>>(nodes, mark, slotof, slotnode, cntp);

    k_layer1<<<3125, 1024, 0, stream>>>(x16, csr, rowptr, deg, fw, wb, raw2_16, g2v4);
    dim3 gl2(BB / 16, 3);
    k_layer2<<<gl2, 1024, 0, stream>>>(raw2_16, csr, rowptr, deg, g2v4, fw, slotnode, cntp, z2);
    k_final<<<BB / 16, 256, 0, stream>>>(flag, nodes, slotof, z2, raw2_16, x16, h, fw, wb, d_out);
}

// Round 9
// 377.775 us; speedup vs baseline: 4.0788x; 1.0949x over previous
//
#include <hip/hip_runtime.h>

#define NN 50000
#define EE 800000
#define BB 4096
#define NB 512       // dst buckets
#define BW 98        // nodes per bucket
#define CAP 2176     // slot capacity per bucket (mean 1568 + ~15 sigma)
#define CH 128       // edge chunks per set in bucketA

// f32 weight-table offsets (elements)
#define OFF_T1W 0
#define OFF_T1B 16384
#define OFF_GW1 16448
#define OFF_GB1 16832
#define OFF_HW1 16848
#define OFF_GW2 29136
#define OFF_GB2 30288
#define OFF_HW2 30304
#define OFF_T2W 67168
#define OFF_T2B 112224
#define OFF_T3W 112288
#define OFF_T3B 112416
#define WTOT    112418
#define WPAD    112640   // 440*256

// bf16 weight table (MFMA B-operands)
#define WB_T1W  0        // t1w native [64][256]
#define WB_HW1T 16384    // 3 x hw1^T [64][64]
#define WB_HW2T 28672    // 3 x hw2^T [64][192]
#define WB_T2W  65536    // t2w native [64][704]
#define WB_TOT  110592

typedef __attribute__((ext_vector_type(8))) short bf16x8;
typedef __attribute__((ext_vector_type(4))) float f32x4;

__device__ __forceinline__ float bf2f(unsigned short u) {
    return __uint_as_float(((unsigned int)u) << 16);
}
__device__ __forceinline__ unsigned short f2bf(float f) {
    unsigned int u = __float_as_uint(f);
    u = (u + 0x7fffu + ((u >> 16) & 1u)) >> 16;
    return (unsigned short)u;
}
__device__ __forceinline__ float leakyf(float v) { return v >= 0.f ? v : 0.3f * v; }
__device__ __forceinline__ float tanh_fast(float v) {
    float e = __expf(2.f * v);
    return 1.f - 2.f / (e + 1.f);
}
__device__ __forceinline__ int rfl(int v) { return __builtin_amdgcn_readfirstlane(v); }

// inline per-wave dtype sniff: 0 = bf16, 1 = f32 (reads first 128 B of h; wave-uniform)
__device__ __forceinline__ int sniff_wave(const unsigned short* hs) {
    int lane = threadIdx.x & 63;
    unsigned short s = hs[2 * lane];
    int ef = (s >> 7) & 0xFF;
    unsigned long long m = __ballot(ef >= 100 && ef <= 132);
    return (__popcll(m) >= 40) ? 0 : 1;
}

// ---------- convert all weights: f32 table + bf16 MFMA table, inline sniff ----------
__global__ __launch_bounds__(256) void k_convert(
    const unsigned short* __restrict__ hs,
    const void* t1w, const void* t1b,
    const void* gw1a, const void* gw1b, const void* gw1c,
    const void* gb1a, const void* gb1b, const void* gb1c,
    const void* hw1a, const void* hw1b, const void* hw1c,
    const void* gw2a, const void* gw2b, const void* gw2c,
    const void* gb2a, const void* gb2b, const void* gb2c,
    const void* hw2a, const void* hw2b, const void* hw2c,
    const void* t2w, const void* t2b, const void* t3w, const void* t3b,
    float* __restrict__ fw, unsigned short* __restrict__ wb) {
    const int starts[24] = {0, 16384, 16448, 16576, 16704, 16832, 16833, 16834,
                            16848, 20944, 25040, 29136, 29520, 29904, 30288, 30289, 30290,
                            30304, 42592, 54880, 67168, 112224, 112288, 112416};
    const int cnts[24] = {16384, 64, 128, 128, 128, 1, 1, 1, 4096, 4096, 4096,
                          384, 384, 384, 1, 1, 1, 12288, 12288, 12288, 45056, 64, 128, 2};
    const void* sp[24] = {t1w, t1b, gw1a, gw1b, gw1c, gb1a, gb1b, gb1c, hw1a, hw1b, hw1c,
                          gw2a, gw2b, gw2c, gb2a, gb2b, gb2c, hw2a, hw2b, hw2c, t2w, t2b, t3w, t3b};
    int isf32 = sniff_wave(hs);
    int idx = blockIdx.x * 256 + threadIdx.x;
    if (idx < WTOT) {
        float v = 0.f;
#pragma unroll
        for (int k = 0; k < 24; ++k) {
            int lo = idx - starts[k];
            if (lo >= 0 && lo < cnts[k])
                v = isf32 ? ((const float*)sp[k])[lo] : bf2f(((const unsigned short*)sp[k])[lo]);
        }
        fw[idx] = v;
    } else if (idx >= WPAD && idx < WPAD + WB_TOT) {
        int i2 = idx - WPAD;
        const void* p;
        int srci;
        if (i2 < WB_HW1T) {
            p = t1w; srci = i2;
        } else if (i2 < WB_HW2T) {
            int rel = i2 - WB_HW1T;
            int set = rel >> 12, r2 = rel & 4095;
            int jj = r2 >> 6, kk = r2 & 63;
            p = set == 0 ? hw1a : (set == 1 ? hw1b : hw1c);
            srci = kk * 64 + jj;
        } else if (i2 < WB_T2W) {
            int rel = i2 - WB_HW2T;
            int set = rel / 12288, r2 = rel % 12288;
            int n = r2 / 192, k = r2 % 192;
            p = set == 0 ? hw2a : (set == 1 ? hw2b : hw2c);
            srci = k * 64 + n;
        } else {
            p = t2w; srci = i2 - WB_T2W;
        }
        wb[i2] = isf32 ? f2bf(((const float*)p)[srci]) : ((const unsigned short*)p)[srci];
    }
}

// ---------- multi-split bucket scatter: two-pass LDS histogram, slot-capped buckets ----------
__global__ __launch_bounds__(256) void k_bucketA(const int* __restrict__ s0, const int* __restrict__ s1,
                                                 const int* __restrict__ s2, const int* __restrict__ d0,
                                                 const int* __restrict__ d1, const int* __restrict__ d2,
                                                 int* __restrict__ gcur, unsigned int* __restrict__ tmp) {
    int set = blockIdx.y;
    const int* ss = set == 0 ? s0 : (set == 1 ? s1 : s2);
    const int* dd = set == 0 ? d0 : (set == 1 ? d1 : d2);
    __shared__ int hist[NB];
    __shared__ int lcur[NB];
    int tid = threadIdx.x;
    for (int i = tid; i < NB; i += 256) { hist[i] = 0; lcur[i] = 0; }
    __syncthreads();
    int e0 = blockIdx.x * (EE / CH);
    int e1 = e0 + (EE / CH);
    for (int t = e0 + tid; t < e1; t += 256)
        atomicAdd(&hist[dd[t] / BW], 1);
    __syncthreads();
    for (int b = tid; b < NB; b += 256) {
        int hh = hist[b];
        if (hh > 0) hist[b] = atomicAdd(&gcur[set * NB + b], hh);
    }
    __syncthreads();
    unsigned int* tp = tmp + (size_t)set * NB * CAP;
    for (int t = e0 + tid; t < e1; t += 256) {
        int d = dd[t], s = ss[t];
        int b = d / BW;
        int r = atomicAdd(&lcur[b], 1);
        int pos = hist[b] + r;
        if (pos < CAP) tp[(size_t)b * CAP + pos] = (unsigned)s | ((unsigned)(d - b * BW) << 16);
    }
}

// ---------- per-bucket: node degrees, rowptr (slot-relative), rsqrt d ----------
__global__ __launch_bounds__(256) void k_rowptr(const int* __restrict__ gcur,
                                                const unsigned int* __restrict__ tmp,
                                                int* __restrict__ deg, int* __restrict__ rowptr,
                                                float* __restrict__ g1, float* __restrict__ g2) {
    int b = blockIdx.x, set = blockIdx.y;
    int nb = b * BW;
    if (nb >= NN) return;
    __shared__ int hist[BW];
    __shared__ int rp[BW];
    int tid = threadIdx.x;
    int nv = NN - nb < BW ? NN - nb : BW;
    if (tid < BW) hist[tid] = 0;
    __syncthreads();
    int cnt = gcur[set * NB + b];
    if (cnt > CAP) cnt = CAP;
    const unsigned int* tp = tmp + (size_t)set * NB * CAP + (size_t)b * CAP;
    for (int j = tid; j < cnt; j += 256) atomicAdd(&hist[tp[j] >> 16], 1);
    __syncthreads();
    if (tid == 0) {
        int run = 0;
        for (int i = 0; i < nv; ++i) { rp[i] = run; run += hist[i]; }
    }
    __syncthreads();
    if (tid < nv) {
        int dg = hist[tid];
        size_t n = (size_t)set * NN + nb + tid;
        deg[n] = dg;
        rowptr[n] = b * CAP + rp[tid];
        float v = dg > 0 ? rsqrtf((float)dg) : 0.f;
        g1[n * 4 + 2] = v;
        g2[n * 4 + 2] = v;
    }
}

// ---------- input transform via MFMA: x = leaky(h @ t1w^T + b), fused p1 gate dots ----------
__global__ __launch_bounds__(256) void k_input(const void* __restrict__ hB,
                                               const unsigned short* __restrict__ wb,
                                               const float* __restrict__ fw,
                                               unsigned short* __restrict__ x16,
                                               float4* __restrict__ g1v4) {
    __shared__ float xt[16][65];
    int tid = threadIdx.x, lane = tid & 63, wid = tid >> 6;
    int m = lane & 15, q = lane >> 4;
    int node0 = blockIdx.x * 16;
    int isf32 = sniff_wave((const unsigned short*)hB);
    f32x4 acc = {0.f, 0.f, 0.f, 0.f};
    const unsigned short* bsrc = wb + WB_T1W + ((size_t)(wid * 16 + m)) * 256 + q * 8;
    if (isf32) {
        const float* ap = (const float*)hB + (size_t)(node0 + m) * 256 + q * 8;
        for (int k0 = 0; k0 < 256; k0 += 32) {
            float4 f0 = *(const float4*)(ap + k0);
            float4 f1 = *(const float4*)(ap + k0 + 4);
            bf16x8 a;
            a[0] = (short)f2bf(f0.x); a[1] = (short)f2bf(f0.y);
            a[2] = (short)f2bf(f0.z); a[3] = (short)f2bf(f0.w);
            a[4] = (short)f2bf(f1.x); a[5] = (short)f2bf(f1.y);
            a[6] = (short)f2bf(f1.z); a[7] = (short)f2bf(f1.w);
            bf16x8 b = *(const bf16x8*)(bsrc + k0);
            acc = __builtin_amdgcn_mfma_f32_16x16x32_bf16(a, b, acc, 0, 0, 0);
        }
    } else {
        const unsigned short* ap = (const unsigned short*)hB + (size_t)(node0 + m) * 256 + q * 8;
        for (int k0 = 0; k0 < 256; k0 += 32) {
            bf16x8 a = *(const bf16x8*)(ap + k0);
            bf16x8 b = *(const bf16x8*)(bsrc + k0);
            acc = __builtin_amdgcn_mfma_f32_16x16x32_bf16(a, b, acc, 0, 0, 0);
        }
    }
    int gcol = wid * 16 + m;
    float bias = fw[OFF_T1B + gcol];
#pragma unroll
    for (int r = 0; r < 4; ++r) {
        int row = q * 4 + r;
        float v = leakyf(acc[r] + bias);
        x16[(size_t)(node0 + row) * 64 + gcol] = f2bf(v);
        xt[row][gcol] = v;
    }
    __syncthreads();
    int nl = wid * 4 + q;
    int node = node0 + nl;
    float xv[4];
#pragma unroll
    for (int r = 0; r < 4; ++r) xv[r] = xt[nl][m + 16 * r];
#pragma unroll
    for (int set = 0; set < 3; ++set) {
        const float* gw = fw + OFF_GW1 + set * 128;
        float pd = 0.f, ps = 0.f;
#pragma unroll
        for (int r = 0; r < 4; ++r) {
            int c = m + 16 * r;
            pd = fmaf(xv[r], gw[c], pd);
            ps = fmaf(xv[r], gw[64 + c], ps);
        }
        pd += __shfl_xor(pd, 1); ps += __shfl_xor(ps, 1);
        pd += __shfl_xor(pd, 2); ps += __shfl_xor(ps, 2);
        pd += __shfl_xor(pd, 4); ps += __shfl_xor(ps, 4);
        pd += __shfl_xor(pd, 8); ps += __shfl_xor(ps, 8);
        if (m == 0) {
            float2* p = (float2*)&g1v4[(size_t)set * NN + node];
            *p = make_float2(ps, pd);   // .x=ps, .y=pd
        }
    }
}

// ---------- bucket phase B: LDS cursors + fused gate -> 4B CSR recs (localized writes) ----------
__global__ __launch_bounds__(256) void k_bucketB(const int* __restrict__ gcur,
                                                 const unsigned int* __restrict__ tmp,
                                                 const int* __restrict__ rowptr,
                                                 const float4* __restrict__ g1v4,
                                                 const float* __restrict__ fw,
                                                 unsigned int* __restrict__ csr) {
    int b = blockIdx.x, set = blockIdx.y;
    int nb = b * BW;
    if (nb >= NN) return;
    __shared__ float4 gdw[BW];
    __shared__ int cur[BW];
    __shared__ int rpl[BW];
    int tid = threadIdx.x;
    int nv = NN - nb < BW ? NN - nb : BW;
    if (tid < nv) {
        gdw[tid] = g1v4[(size_t)set * NN + nb + tid];
        rpl[tid] = rowptr[(size_t)set * NN + nb + tid];
        cur[tid] = 0;
    }
    __syncthreads();
    int cnt = gcur[set * NB + b];
    if (cnt > CAP) cnt = CAP;
    float gbv = fw[OFF_GB1 + set];
    const float4* gv = g1v4 + (size_t)set * NN;
    const unsigned int* tp = tmp + (size_t)set * NB * CAP + (size_t)b * CAP;
    unsigned int* cp = csr + (size_t)set * NB * CAP;
    for (int j = tid; j < cnt; j += 256) {
        unsigned rec = tp[j];
        int s = rec & 0xFFFF;
        int dl = rec >> 16;
        float4 gs = gv[s];
        float4 gd = gdw[dl];
        float a = tanh_fast(gd.y + gs.x + gbv);
        float e = a * gd.z * gs.z;
        int rank = atomicAdd(&cur[dl], 1);
        cp[rpl[dl] + rank] = (unsigned)s | ((unsigned)f2bf(e) << 16);
    }
}

// ---------- fused layer 1 + p2: uint2 gathers (4 edges/instr), MFMA epilogue ----------
__global__ __launch_bounds__(1024) void k_layer1(const unsigned short* __restrict__ x16,
                                                 const unsigned int* __restrict__ csr,
                                                 const int* __restrict__ rowptr,
                                                 const int* __restrict__ deg,
                                                 const float* __restrict__ fw,
                                                 const unsigned short* __restrict__ wb,
                                                 unsigned short* __restrict__ raw2_16,
                                                 float4* __restrict__ g2v4) {
    __shared__ unsigned short tb[3][16][72];   // t vectors per set (MFMA A rows)
    __shared__ unsigned short r2l[16][200];    // raw2 of 16 nodes (192 + pad)
    int tid = threadIdx.x, lane = tid & 63, wid = tid >> 6;
    int g = lane >> 4, f = lane & 15;          // edge group, feature slice (4 feats)
    int node = blockIdx.x * 16 + wid;
#pragma unroll
    for (int set = 0; set < 3; ++set) {
        int start = rfl(rowptr[(size_t)set * NN + node]);
        int cnt = rfl(deg[(size_t)set * NN + node]);
        const unsigned int* cs = csr + (size_t)set * NB * CAP + start;
        float a0 = 0.f, a1 = 0.f, a2 = 0.f, a3 = 0.f;
        int j = 0;
        for (; j + 8 <= cnt; j += 8) {
#pragma unroll
            for (int k2 = 0; k2 < 2; ++k2) {
                unsigned rec = cs[j + 4 * k2 + g];
                float e = bf2f((unsigned short)(rec >> 16));
                uint2 u = *(const uint2*)(x16 + (size_t)(rec & 0xFFFF) * 64 + 4 * f);
                a0 = fmaf(bf2f((unsigned short)(u.x & 0xFFFF)), e, a0);
                a1 = fmaf(bf2f((unsigned short)(u.x >> 16)), e, a1);
                a2 = fmaf(bf2f((unsigned short)(u.y & 0xFFFF)), e, a2);
                a3 = fmaf(bf2f((unsigned short)(u.y >> 16)), e, a3);
            }
        }
#pragma unroll
        for (int t = 0; t < 2; ++t) {
            int idx = j + 4 * t + g;
            if (idx < cnt) {
                unsigned rec = cs[idx];
                float e = bf2f((unsigned short)(rec >> 16));
                uint2 u = *(const uint2*)(x16 + (size_t)(rec & 0xFFFF) * 64 + 4 * f);
                a0 = fmaf(bf2f((unsigned short)(u.x & 0xFFFF)), e, a0);
                a1 = fmaf(bf2f((unsigned short)(u.x >> 16)), e, a1);
                a2 = fmaf(bf2f((unsigned short)(u.y & 0xFFFF)), e, a2);
                a3 = fmaf(bf2f((unsigned short)(u.y >> 16)), e, a3);
            }
        }
        a0 += __shfl_xor(a0, 16); a0 += __shfl_xor(a0, 32);
        a1 += __shfl_xor(a1, 16); a1 += __shfl_xor(a1, 32);
        a2 += __shfl_xor(a2, 16); a2 += __shfl_xor(a2, 32);
        a3 += __shfl_xor(a3, 16); a3 += __shfl_xor(a3, 32);
        if (g == 0) {
            uint2 ur = *(const uint2*)(x16 + (size_t)node * 64 + 4 * f);
            float t0 = fmaf(0.3f, bf2f((unsigned short)(ur.x & 0xFFFF)), a0);
            float t1 = fmaf(0.3f, bf2f((unsigned short)(ur.x >> 16)), a1);
            float t2 = fmaf(0.3f, bf2f((unsigned short)(ur.y & 0xFFFF)), a2);
            float t3 = fmaf(0.3f, bf2f((unsigned short)(ur.y >> 16)), a3);
            uint2 pk;
            pk.x = (unsigned)f2bf(t0) | ((unsigned)f2bf(t1) << 16);
            pk.y = (unsigned)f2bf(t2) | ((unsigned)f2bf(t3) << 16);
            *(uint2*)&tb[set][wid][4 * f] = pk;
        }
    }
    __syncthreads();
    int m = lane & 15, q = lane >> 4;
    if (wid < 12) {
        int set = wid >> 2, sw = wid & 3;
        f32x4 c4 = {0.f, 0.f, 0.f, 0.f};
        const unsigned short* bp = wb + WB_HW1T + set * 4096 + (sw * 16 + m) * 64 + q * 8;
#pragma unroll
        for (int k0 = 0; k0 < 64; k0 += 32) {
            bf16x8 a = *(const bf16x8*)&tb[set][m][k0 + q * 8];
            bf16x8 b = *(const bf16x8*)(bp + k0);
            c4 = __builtin_amdgcn_mfma_f32_16x16x32_bf16(a, b, c4, 0, 0, 0);
        }
        int gcol = sw * 16 + m;
#pragma unroll
        for (int r = 0; r < 4; ++r) {
            int row = q * 4 + r;
            unsigned short v = f2bf(leakyf(c4[r]));
            raw2_16[(size_t)(blockIdx.x * 16 + row) * 192 + set * 64 + gcol] = v;
            r2l[row][set * 64 + gcol] = v;
        }
    }
    __syncthreads();
    // fused p2: wave wid handles node wid; lane covers 3 features each
    float pd[3] = {0.f, 0.f, 0.f}, ps[3] = {0.f, 0.f, 0.f};
    float rv[3];
#pragma unroll
    for (int t = 0; t < 3; ++t) rv[t] = bf2f(r2l[wid][lane * 3 + t]);
#pragma unroll
    for (int set = 0; set < 3; ++set) {
        const float* gg = fw + OFF_GW2 + set * 384;
#pragma unroll
        for (int t = 0; t < 3; ++t) {
            int cc = lane * 3 + t;
            pd[set] = fmaf(rv[t], gg[cc], pd[set]);
            ps[set] = fmaf(rv[t], gg[192 + cc], ps[set]);
        }
    }
#pragma unroll
    for (int mm = 32; mm >= 1; mm >>= 1) {
#pragma unroll
        for (int set = 0; set < 3; ++set) {
            pd[set] += __shfl_xor(pd[set], mm);
            ps[set] += __shfl_xor(ps[set], mm);
        }
    }
    if (lane == 0) {
#pragma unroll
        for (int set = 0; set < 3; ++set) {
            float2* p = (float2*)&g2v4[(size_t)set * NN + node];
            *p = make_float2(ps[set], pd[set]);   // .x=ps, .y=pd (keep .z = d)
        }
    }
}

// ---------- merged layer2 + final: 16 batch rows/block, inline gate agg + MFMA GEMMs ----------
__global__ __launch_bounds__(1024) void k_final(const int* __restrict__ nodes,
                                                const unsigned short* __restrict__ raw2_16,
                                                const unsigned short* __restrict__ x16,
                                                const void* __restrict__ hB,
                                                const unsigned int* __restrict__ csr,
                                                const int* __restrict__ rowptr,
                                                const int* __restrict__ deg,
                                                const float4* __restrict__ g2v4,
                                                const float* __restrict__ fw,
                                                const unsigned short* __restrict__ wb,
                                                void* __restrict__ outv) {
    __shared__ unsigned short nfb[16][712];    // 22.8 KB: [192 h2 | 256 h | 64 x | 192 raw2]
    __shared__ unsigned short tbb3[16][584];   // 18.7 KB: 3 sets x 192 (+8 pad)
    __shared__ float sarr[16][64];
    __shared__ int nd[16];
    int tid = threadIdx.x, lane = tid & 63, wid = tid >> 6;
    int b0 = blockIdx.x * 16;
    int isf32 = sniff_wave((const unsigned short*)hB);
    if (tid < 16) nd[tid] = nodes[b0 + tid];
    __syncthreads();
    for (int idx = tid; idx < 16 * 256; idx += 1024) {
        int row = idx >> 8, c = idx & 255;
        size_t hi = (size_t)nd[row] * 256 + c;
        nfb[row][192 + c] = isf32 ? f2bf(((const float*)hB)[hi]) : ((const unsigned short*)hB)[hi];
    }
    for (int idx = tid; idx < 16 * 64; idx += 1024) {
        int row = idx >> 6, c = idx & 63;
        nfb[row][448 + c] = x16[(size_t)nd[row] * 64 + c];
    }
    for (int idx = tid; idx < 16 * 192; idx += 1024) {
        int row = idx / 192, c = idx % 192;
        nfb[row][512 + c] = raw2_16[(size_t)nd[row] * 192 + c];
    }
    __syncthreads();
    // phase A: wave wid aggregates its row's node over 3 sets (split-half, inline gate)
    {
        int node = rfl(nd[wid]);
        int half = lane >> 5, c = lane & 31;
#pragma unroll
        for (int set = 0; set < 3; ++set) {
            int start = rfl(rowptr[(size_t)set * NN + node]);
            int cnt = rfl(deg[(size_t)set * NN + node]);
            float4 gn = g2v4[(size_t)set * NN + node];
            float pdv = gn.y, dnd = gn.z;
            float gbv = fw[OFF_GB2 + set];
            const unsigned int* cs = csr + (size_t)set * NB * CAP + start;
            const float4* gv = g2v4 + (size_t)set * NN;
            float a[6] = {0.f, 0.f, 0.f, 0.f, 0.f, 0.f};
            int j = 0;
            for (; j + 2 <= cnt; j += 2) {
                unsigned rec = cs[j + half];
                int s = rec & 0xFFFF;
                float4 gg = gv[s];
                float e = tanh_fast(pdv + gg.x + gbv) * dnd * gg.z;
                const unsigned short* r = raw2_16 + (size_t)s * 192;
#pragma unroll
                for (int blk = 0; blk < 3; ++blk) {
                    unsigned u = *(const unsigned*)(r + blk * 64 + 2 * c);
                    a[2 * blk] = fmaf(bf2f((unsigned short)(u & 0xFFFF)), e, a[2 * blk]);
                    a[2 * blk + 1] = fmaf(bf2f((unsigned short)(u >> 16)), e, a[2 * blk + 1]);
                }
            }
            if (j < cnt && half == 0) {
                unsigned rec = cs[j];
                int s = rec & 0xFFFF;
                float4 gg = gv[s];
                float e = tanh_fast(pdv + gg.x + gbv) * dnd * gg.z;
                const unsigned short* r = raw2_16 + (size_t)s * 192;
#pragma unroll
                for (int blk = 0; blk < 3; ++blk) {
                    unsigned u = *(const unsigned*)(r + blk * 64 + 2 * c);
                    a[2 * blk] = fmaf(bf2f((unsigned short)(u & 0xFFFF)), e, a[2 * blk]);
                    a[2 * blk + 1] = fmaf(bf2f((unsigned short)(u >> 16)), e, a[2 * blk + 1]);
                }
            }
#pragma unroll
            for (int i = 0; i < 6; ++i) a[i] += __shfl_xor(a[i], 32);
            if (half == 0) {
#pragma unroll
                for (int blk = 0; blk < 3; ++blk) {
                    int fc0 = blk * 64 + 2 * c;
                    float r20 = bf2f(nfb[wid][512 + fc0]);
                    float r21 = bf2f(nfb[wid][512 + fc0 + 1]);
                    tbb3[wid][set * 192 + fc0] = f2bf(fmaf(0.3f, r20, a[2 * blk]));
                    tbb3[wid][set * 192 + fc0 + 1] = f2bf(fmaf(0.3f, r21, a[2 * blk + 1]));
                }
            }
        }
    }
    __syncthreads();
    // phase B: hw2 GEMMs, 12 waves in parallel (set = wid>>2, sw = wid&3)
    int m = lane & 15, q = lane >> 4;
    if (wid < 12) {
        int set = wid >> 2, sw = wid & 3;
        f32x4 c4 = {0.f, 0.f, 0.f, 0.f};
        const unsigned short* bp = wb + WB_HW2T + set * 12288 + (sw * 16 + m) * 192 + q * 8;
#pragma unroll
        for (int k0 = 0; k0 < 192; k0 += 32) {
            bf16x8 a = *(const bf16x8*)&tbb3[m][set * 192 + k0 + q * 8];
            bf16x8 bf = *(const bf16x8*)(bp + k0);
            c4 = __builtin_amdgcn_mfma_f32_16x16x32_bf16(a, bf, c4, 0, 0, 0);
        }
        int col = sw * 16 + m;
#pragma unroll
        for (int r = 0; r < 4; ++r)
            nfb[q * 4 + r][set * 64 + col] = f2bf(leakyf(c4[r]));
    }
    __syncthreads();
    // phase C: t2 GEMM (4 waves), outputs
    if (wid < 4) {
        f32x4 c4 = {0.f, 0.f, 0.f, 0.f};
        const unsigned short* bp = wb + WB_T2W + (wid * 16 + m) * 704 + q * 8;
#pragma unroll
        for (int k0 = 0; k0 < 704; k0 += 32) {
            bf16x8 a = *(const bf16x8*)&nfb[m][k0 + q * 8];
            bf16x8 bf = *(const bf16x8*)(bp + k0);
            c4 = __builtin_amdgcn_mfma_f32_16x16x32_bf16(a, bf, c4, 0, 0, 0);
        }
        int col = wid * 16 + m;
        float bias = fw[OFF_T2B + col];
#pragma unroll
        for (int r = 0; r < 4; ++r) {
            int row = q * 4 + r;
            float sv = leakyf(c4[r] + bias);
            sarr[row][col] = sv;
            size_t oi = 8192 + (size_t)(b0 + row) * 64 + col;
            if (isf32) ((float*)outv)[oi] = sv;
            else ((unsigned short*)outv)[oi] = f2bf(sv);
        }
    }
    __syncthreads();
    if (tid < 32) {
        int row = tid >> 1, oc = tid & 1;
        float acc2 = fw[OFF_T3B + oc];
        const float* tw = fw + OFF_T3W + oc * 64;
#pragma unroll 8
        for (int c = 0; c < 64; ++c) acc2 = fmaf(sarr[row][c], tw[c], acc2);
        size_t oi = (size_t)(b0 + row) * 2 + oc;
        if (isf32) ((float*)outv)[oi] = acc2;
        else ((unsigned short*)outv)[oi] = f2bf(acc2);
    }
}

extern "C" void kernel_launch(void* const* d_in, const int* in_sizes, int n_in,
                              void* d_out, int out_size, void* d_ws, size_t ws_size,
                              hipStream_t stream) {
    const void* h = d_in[0];
    const int* src1 = (const int*)d_in[1];
    const int* dst1 = (const int*)d_in[2];
    const int* src2 = (const int*)d_in[3];
    const int* dst2 = (const int*)d_in[4];
    const int* src3 = (const int*)d_in[5];
    const int* dst3 = (const int*)d_in[6];
    const int* nodes = (const int*)d_in[7];

    char* w = (char*)d_ws;
    size_t off = 0;
    auto carve = [&](size_t bytes) -> void* {
        void* p = w + off;
        off += (bytes + 255) & ~(size_t)255;
        return p;
    };
    int* gcur = (int*)carve((size_t)3 * NB * 4);       // zeroed
    int* deg = (int*)carve((size_t)3 * NN * 4);
    int* rowptr = (int*)carve((size_t)3 * NN * 4);
    float4* g1v4 = (float4*)carve((size_t)3 * NN * 16);
    float4* g2v4 = (float4*)carve((size_t)3 * NN * 16);
    unsigned int* tmp = (unsigned int*)carve((size_t)3 * NB * CAP * 4);
    unsigned int* csr = (unsigned int*)carve((size_t)3 * NB * CAP * 4);
    float* fw = (float*)carve((size_t)WTOT * 4);
    unsigned short* wb = (unsigned short*)carve((size_t)WB_TOT * 2);
    unsigned short* x16 = (unsigned short*)carve((size_t)NN * 64 * 2);
    unsigned short* raw2_16 = (unsigned short*)carve((size_t)NN * 192 * 2);

    hipMemsetAsync(gcur, 0, (size_t)3 * NB * 4, stream);

    k_convert<<<(WPAD + WB_TOT) / 256, 256, 0, stream>>>(
        (const unsigned short*)h,
        d_in[8], d_in[9],
        d_in[10], d_in[16], d_in[22],
        d_in[11], d_in[17], d_in[23],
        d_in[12], d_in[18], d_in[24],
        d_in[13], d_in[19], d_in[25],
        d_in[14], d_in[20], d_in[26],
        d_in[15], d_in[21], d_in[27],
        d_in[28], d_in[29], d_in[30], d_in[31], fw, wb);

    dim3 gch(CH, 3);
    k_bucketA<<<gch, 256, 0, stream>>>(src1, src2, src3, dst1, dst2, dst3, gcur, tmp);
    dim3 gb(NB, 3);
    k_rowptr<<<gb, 256, 0, stream>>>(gcur, tmp, deg, rowptr, (float*)g1v4, (float*)g2v4);

    k_input<<<3125, 256, 0, stream>>>(h, wb, fw, x16, g1v4);
    k_bucketB<<<gb, 256, 0, stream>>>(gcur, tmp, rowptr, g1v4, fw, csr);

    k_layer1<<<3125, 1024, 0, stream>>>(x16, csr, rowptr, deg, fw, wb, raw2_16, g2v4);
    k_final<<<BB / 16, 1024, 0, stream>>>(nodes, raw2_16, x16, h, csr, rowptr, deg, g2v4,
                                          fw, wb, d_out);
}